// Round 20
// baseline (209.054 us; speedup 1.0000x reference)
//
#include <hip/hip_runtime.h>
#include <hip/hip_bf16.h>
#include <math.h>

#define BB 64
#define PB_STRIDE 1536      // >= 64 b * 17 jtiles
#define CONV_SIDE 2129920   // bf16 elems per side (64*128*260 max)

typedef __attribute__((ext_vector_type(8))) short short8;
typedef __attribute__((ext_vector_type(4))) short short4v;
typedef __attribute__((ext_vector_type(4))) float f32x4;

// workspace layout (floats)
#define WS_ACC    0
#define WS_BNA    8
#define WS_BNB    264
#define WS_FTAB   520
#define WS_ROWW   536
#define WS_SLRS   1064
#define WS_WBF1   1128     // 1024 shorts (32 o x 64 K)
#define WS_WBF2   2152     // 16384 shorts
#define WS_WBF3   10344    // 65536 shorts
#define WS_PART1  43112    // 393216
#define WS_PART2  436328   // 393216
#define WS_NORMS  829544   // 66560
#define WS_BMAX   896104   // 64
#define WS_XPAD   896168   // 2228224 floats padded bf16 conv inputs
#define WS_CONV   3124392  // 2129920 floats = 2 sides x CONV_SIDE bf16
#define WS_ZB16   5254312  // 1100000
#define WS_ZFRAG  6354312  // 1120000 floats (fragment-packed z)
#define WS_TOTAL  7474312

// d_out layout (floats)
#define O_LG1  0
#define O_LG2  320
#define O_A1   640
#define O_A2   (640 + 1064960)
#define O_LOSS (O_A2 + 1064960)

#define LOG2E 1.44269504f
#define LN2   0.69314718f

// hardware v_exp_f32: exact enough on our guaranteed arg range [-222, 110]
#define EXP2F(x) __builtin_amdgcn_exp2f(x)

__device__ __forceinline__ short f2bf(float f) {
  unsigned u = __float_as_uint(f);
  u += 0x7FFFu + ((u >> 16) & 1u);
  return (short)(u >> 16);
}
__device__ __forceinline__ float bfb2f(short s) {
  return __uint_as_float(((unsigned)(unsigned short)s) << 16);
}

// ---------- fused prep: init + all weight preps + aug pad (grid 457) ----------
__global__ void prep_k(double* acc, const float* __restrict__ sl, float* __restrict__ slrs,
                       const float* __restrict__ w1, const float* __restrict__ w2,
                       const float* __restrict__ w3, short* __restrict__ o1,
                       short* __restrict__ o2, short* __restrict__ o3,
                       const float* __restrict__ a1, const float* __restrict__ a2,
                       short* __restrict__ xp) {
  int bid = blockIdx.x;
  if (bid == 0) {
    if (threadIdx.x == 0) *acc = 0.0;
    if (threadIdx.x < 64) {
      int r = threadIdx.x;
      float s = 0.f;
      for (int c = 0; c < 64; ++c) s += sl[r * 64 + c];
      slrs[r] = s;
    }
    return;
  }
  if (bid <= 328) {
    int i = (bid - 1) * 256 + threadIdx.x;
    const float* w; short* ob; int CIN, CIPAD;
    if (i < 2048)        { w = w1; ob = o1; CIN = 1;  CIPAD = 8; }
    else if (i < 18432)  { i -= 2048;  w = w2; ob = o2; CIN = 32; CIPAD = 32; }
    else                 { i -= 18432; w = w3; ob = o3; CIN = 64; CIPAD = 64; }
    int KTOT = CIPAD * 8;
    int o = i / KTOT, q = i - o * KTOT;
    int k = q / CIPAD, ci = q - k * CIPAD;
    short v = 0;
    if (ci < CIN) v = f2bf(w[(o * CIN + ci) * 8 + k]);
    ob[i] = v;
    return;
  }
  int sb = bid - 329;
  int side = sb >> 6, b = sb & 63;
  const float* src = (side ? a2 : a1) + (size_t)b * 1024;
  short* dst = xp + (size_t)sb * 1032;
  for (int e = threadIdx.x; e < 1032; e += 256) {
    short v = 0;
    if (e >= 4 && e < 1028) v = f2bf(src[e - 4]);
    dst[e] = v;
  }
}

// ---------- K-permuted MFMA conv1d, weights staged to LDS (swizzled) ----------
template <int CIN, int CIPAD, int COUT, int OSPLIT, int XP, int LRS>
__launch_bounds__(256)
__global__ void conv4_k(const short* __restrict__ xbf, const short* __restrict__ wbf,
                        short* __restrict__ ybf, float* __restrict__ part_s,
                        float* __restrict__ part_s2, int Lc, int Lcp) {
  constexpr int KTOT = CIPAD * 8;
  constexpr int S = KTOT / 32;
  constexpr int COS = COUT / OSPLIT;
  constexpr int NT = COS / 16;
  constexpr int RSd = LRS / 2;
  constexpr int CP2 = CIPAD / 2;
  __shared__ __attribute__((aligned(16))) unsigned traw[72 * RSd];
  __shared__ __attribute__((aligned(16))) char wlds[COS * KTOT * 2];
  __shared__ float ps[4][COS], ps2[4][COS];
  const int tid = threadIdx.x;
  const int wave = tid >> 6, lane = tid & 63, l15 = lane & 15, l4 = lane >> 4;
  const int by = blockIdx.y;
  const int b = by & 63, side = by >> 6;
  const int o0 = blockIdx.z * COS;
  const int j0 = blockIdx.x * 64;
  const short* xb = xbf + (size_t)(side * 64 + b) * CIN * XP;
  short* yside = ybf + (size_t)side * CONV_SIDE;

  for (int idx = tid; idx < COS * (KTOT / 8); idx += 256) {
    int o = idx / (KTOT / 8);
    int q8 = idx - o * (KTOT / 8);
    short8 wv = *(const short8*)(wbf + (size_t)(o0 + o) * KTOT + q8 * 8);
    unsigned byte = (unsigned)((o * KTOT + q8 * 8) * 2) ^ (unsigned)((o & 7) << 4);
    *(short8*)(wlds + byte) = wv;
  }
  for (int idx = tid; idx < 9 * CP2; idx += 256) {
    int cp = idx & (CP2 - 1);
    int u = idx / CP2;
    int ci = cp * 2;
    short8 av = (short8){0, 0, 0, 0, 0, 0, 0, 0};
    short8 bv = (short8){0, 0, 0, 0, 0, 0, 0, 0};
    if (ci < CIN)     av = *(const short8*)(xb + (size_t)ci * XP + j0 + u * 8);
    if (ci + 1 < CIN) bv = *(const short8*)(xb + (size_t)(ci + 1) * XP + j0 + u * 8);
#pragma unroll
    for (int t = 0; t < 8; ++t)
      traw[(u * 8 + t) * RSd + cp] =
        ((unsigned)(unsigned short)av[t]) | (((unsigned)(unsigned short)bv[t]) << 16);
  }
  __syncthreads();

  f32x4 acc[NT];
#pragma unroll
  for (int nt = 0; nt < NT; ++nt) acc[nt] = (f32x4){0.f, 0.f, 0.f, 0.f};

  const int row = wave * 16 + l15;
  const unsigned wsw = (unsigned)((l15 & 7) << 4);
#pragma unroll
  for (int s = 0; s < S; ++s) {
    int k, cd;
    if (CIPAD == 8)       { k = s * 4 + l4; cd = 0; }
    else if (CIPAD == 32) { k = s;          cd = l4 * 4; }
    else                  { k = s >> 1;     cd = (s & 1) * 16 + l4 * 4; }
    short8 af = *(const short8*)(traw + (row + k) * RSd + cd);
#pragma unroll
    for (int nt = 0; nt < NT; ++nt) {
      unsigned wbyte = (unsigned)(((nt * 16 + l15) * KTOT + s * 32 + l4 * 8) * 2) ^ wsw;
      short8 wv = *(const short8*)(wlds + wbyte);
      acc[nt] = __builtin_amdgcn_mfma_f32_16x16x32_bf16(af, wv, acc[nt], 0, 0, 0);
    }
  }

  const int jbase = j0 + wave * 16 + l4 * 4;
#pragma unroll
  for (int nt = 0; nt < NT; ++nt) {
    int ol = nt * 16 + l15;
    size_t orow = ((size_t)b * COUT + (o0 + ol)) * Lcp;
    float s = 0.f, s2 = 0.f;
    if (jbase + 3 < Lc) {
      short4v sv = (short4v){f2bf(acc[nt][0]), f2bf(acc[nt][1]), f2bf(acc[nt][2]), f2bf(acc[nt][3])};
      *(short4v*)(yside + orow + jbase) = sv;
#pragma unroll
      for (int r = 0; r < 4; ++r) { float v = acc[nt][r]; s += v; s2 = fmaf(v, v, s2); }
    } else {
#pragma unroll
      for (int r = 0; r < 4; ++r) {
        if (jbase + r < Lc) {
          float v = acc[nt][r];
          yside[orow + jbase + r] = f2bf(v);
          s += v; s2 = fmaf(v, v, s2);
        }
      }
    }
    s  += __shfl_xor(s, 16);  s  += __shfl_xor(s, 32);
    s2 += __shfl_xor(s2, 16); s2 += __shfl_xor(s2, 32);
    if (lane < 16) { ps[wave][ol] = s; ps2[wave][ol] = s2; }
  }
  __syncthreads();
  int blk = b * gridDim.x + blockIdx.x;
  for (int o = tid; o < COS; o += 256) {
    size_t pi = (size_t)(side * COUT + o0 + o) * PB_STRIDE + blk;
    part_s [pi] = ps[0][o] + ps[1][o] + ps[2][o] + ps[3][o];
    part_s2[pi] = ps2[0][o] + ps2[1][o] + ps2[2][o] + ps2[3][o];
  }
}

// reduce conv partials -> bnA/bnB per (side, channel)
__global__ void stats2_k(const float* __restrict__ part_s, const float* __restrict__ part_s2,
                         const float* __restrict__ g, const float* __restrict__ beta,
                         float* __restrict__ bnA, float* __restrict__ bnB,
                         int nblk, int n, int COUT) {
  int bid = blockIdx.x;
  int c = bid % COUT;
  float s = 0.f, s2 = 0.f;
  for (int i = threadIdx.x; i < nblk; i += 256) {
    s += part_s[(size_t)bid * PB_STRIDE + i];
    s2 += part_s2[(size_t)bid * PB_STRIDE + i];
  }
#pragma unroll
  for (int off = 32; off; off >>= 1) { s += __shfl_down(s, off); s2 += __shfl_down(s2, off); }
  __shared__ float as[4], as2[4];
  if ((threadIdx.x & 63) == 0) { as[threadIdx.x >> 6] = s; as2[threadIdx.x >> 6] = s2; }
  __syncthreads();
  if (threadIdx.x == 0) {
    float S = as[0] + as[1] + as[2] + as[3];
    float S2 = as2[0] + as2[1] + as2[2] + as2[3];
    float fn = (float)n;
    float mu = S / fn;
    float var = S2 / fn - mu * mu;
    float A = g[c] * rsqrtf(var + 1e-5f);
    bnA[bid] = A;
    bnB[bid] = beta[c] - mu * A;
  }
}

// fused-sides BN-apply + ReLU + maxpool; writes zb, zfrag, optional pooled / next input
__global__ void pool3_k(const short* __restrict__ convb, const float* __restrict__ bnA,
                        const float* __restrict__ bnB, float* __restrict__ pd1,
                        float* __restrict__ pd2, __hip_bfloat16* __restrict__ zb,
                        short* __restrict__ zfrag, int NTt,
                        short* __restrict__ xnext, int TPn,
                        int C, int Lc, int Lcp, int Tout) {
  __shared__ float tile[32][33];
  int bz = blockIdx.z;
  int b = bz & 63, side = bz >> 6;
  const short* cs = convb + (size_t)side * CONV_SIDE;
  float* pooled = side ? pd2 : pd1;
  int zoff = side * Tout;
  int c0 = blockIdx.y * 32;
  int t0 = blockIdx.x * 32;
  int tx = threadIdx.x;
  int ty = threadIdx.y;
  int tid = ty * 32 + tx;
#pragma unroll
  for (int q = 0; q < 4; ++q) {
    int c = c0 + ty + q * 8;
    int t = t0 + tx;
    size_t xrow = xnext ? ((size_t)(side * 64 + b) * C + c) * TPn : 0;
    float v = 0.f;
    if (t < Tout) {
      const short* row = cs + ((size_t)b * C + c) * Lcp;
      float A = bnA[side * C + c], Bb = bnB[side * C + c];
      v = -3.0e38f;
      int p0 = 2 * t - 1;
      if (p0 >= 0) v = fmaxf(v, fmaxf(fmaf(A, bfb2f(row[p0]), Bb), 0.f));
      int p1 = 2 * t;
      if (p1 < Lc) v = fmaxf(v, fmaxf(fmaf(A, bfb2f(row[p1]), Bb), 0.f));
      if (pooled) pooled[((size_t)b * C + c) * Tout + t] = v;
      if (xnext) xnext[xrow + 4 + t] = f2bf(v);
    } else if (xnext && 4 + t < TPn) {
      xnext[xrow + 4 + t] = 0;
    }
    if (xnext && t0 == 0 && tx < 4) xnext[xrow + tx] = 0;
    tile[ty + q * 8][tx] = v;   // tile[c-off][t-off]
  }
  __syncthreads();
  int T2 = 2 * Tout;
#pragma unroll
  for (int q = 0; q < 4; ++q) {
    int t = t0 + ty + q * 8;
    int c = c0 + tx;
    if (t < Tout)
      zb[((size_t)b * T2 + zoff + t) * (size_t)C + c] = __float2bfloat16(tile[tx][ty + q * 8]);
  }
  if (tid < 128) {
    int t_off = tid & 31, cg = tid >> 5;
    if (t0 + t_off < Tout) {
      short8 v;
#pragma unroll
      for (int e = 0; e < 8; ++e) v[e] = f2bf(tile[cg * 8 + e][t_off]);
      int r = zoff + t0 + t_off;
      int ct = r >> 4, l15r = r & 15;
      int ch = c0 + cg * 8;
      int KST = C >> 5;
      int ks = ch >> 5, g4 = (ch >> 3) & 3;
      int lane2 = l15r + (g4 << 4);
      *(short8*)(zfrag + (((size_t)b * NTt + ct) * (size_t)KST + ks) * 512 + (size_t)lane2 * 8) = v;
    }
  }
}

// per-row norms + batch max; block 0 computes ftab/roww; each block zeroes zfrag pad
template <int C>
__global__ void norms_k(const __hip_bfloat16* __restrict__ zb, float* __restrict__ norms,
                        float* __restrict__ bmax, short* __restrict__ zfrag, int NTt,
                        float* __restrict__ ftab, float* __restrict__ roww,
                        int T, float sigma) {
  constexpr int KST = C / 32;
  int b = blockIdx.x;
  int T2 = 2 * T;
  __shared__ float fs[8];
  if (threadIdx.x < 8) {
    double mm = 2.0 / (1.0 + exp((double)threadIdx.x * (double)sigma));
    float f = (mm < 1e-6) ? 0.f : (float)mm;
    fs[threadIdx.x] = f;
    if (b == 0) ftab[threadIdx.x] = f;
  }
  __syncthreads();
  if (b == 0) {
    for (int i = threadIdx.x; i < T; i += 1024) {
      float s = fs[0];
#pragma unroll
      for (int d = 1; d < 8; ++d) s += fs[d] * ((i >= d ? 1.f : 0.f) + (i + d < T ? 1.f : 0.f));
      roww[i] = 2.f * s - fs[0];
    }
  }
  int rem = T2 & 15;
  if (rem) {
    for (int u = threadIdx.x; u < KST * 64; u += 1024) {
      int ks = u >> 6, l = u & 63;
      if ((l & 15) >= rem)
        *(short8*)(zfrag + (((size_t)b * NTt + (NTt - 1)) * (size_t)KST + ks) * 512 + (size_t)l * 8) =
            (short8){0, 0, 0, 0, 0, 0, 0, 0};
    }
  }
  const __hip_bfloat16* zbb = zb + (size_t)b * T2 * C;
  int q = threadIdx.x & 3, r0 = threadIdx.x >> 2;
  float nm = 0.f;
  for (int r = r0; r < T2; r += 256) {
    float s = 0.f;
    const __hip_bfloat16* p = zbb + (size_t)r * C + q * (C / 4);
#pragma unroll
    for (int v = 0; v < C / 32; ++v) {
      short8 sv = *(const short8*)(p + v * 8);
#pragma unroll
      for (int e = 0; e < 8; ++e) { float f = bfb2f(sv[e]); s = fmaf(f, f, s); }
    }
    s += __shfl_xor(s, 1); s += __shfl_xor(s, 2);
    float nr = sqrtf(s);
    if (q == 0) norms[(size_t)b * T2 + r] = nr;
    nm = fmaxf(nm, nr);
  }
#pragma unroll
  for (int off = 32; off; off >>= 1) nm = fmaxf(nm, __shfl_xor(nm, off));
  __shared__ float pm[16];
  if ((threadIdx.x & 63) == 0) pm[threadIdx.x >> 6] = nm;
  __syncthreads();
  if (threadIdx.x == 0) {
    float m = 0.f;
#pragma unroll
    for (int i = 0; i < 16; ++i) m = fmaxf(m, pm[i]);
    bmax[b] = m;
  }
}

__device__ __forceinline__ void block_acc256(float v, double scale, double* acc) {
#pragma unroll
  for (int off = 32; off; off >>= 1) v += __shfl_down(v, off);
  __shared__ float part[4];
  if ((threadIdx.x & 63) == 0) part[threadIdx.x >> 6] = v;
  __syncthreads();
  if (threadIdx.x == 0)
    atomicAdd(acc, (double)(part[0] + part[1] + part[2] + part[3]) * scale);
}

// ---------- FUSED loss kernel: temporal (zfrag MFMA) | band | instance ----------
// XCD-aware swizzle within temporal/band ranges; temporal loop keeps 16 loads in flight.
template <int C>
__launch_bounds__(256)
__global__ void loss_k(const short* __restrict__ zfrag, const __hip_bfloat16* __restrict__ zb,
                       const float* __restrict__ ftab, const float* __restrict__ roww,
                       const float* __restrict__ norms, const float* __restrict__ bmax,
                       const float* __restrict__ sl, const float* __restrict__ slrs,
                       int T, int NTt, int tgx, int bgx,
                       double scale, double* __restrict__ acc) {
  constexpr int KST = C / 32;
  constexpr int LOGK = (KST == 1) ? 0 : (KST == 2) ? 1 : 2;
  constexpr int UNR = 16 / KST;               // 16 loads (256B) in flight per wave
  constexpr int SB_BAND = (78 * (C + 1) + 8) * 4;
  constexpr int SB_INST = 256 * C + 128 * 4 + 16 + 16;
  constexpr int SMEM = SB_BAND > SB_INST ? SB_BAND : SB_INST;
  __shared__ __attribute__((aligned(16))) char smem[SMEM];
  const int tid = threadIdx.x;
  const int wave = tid >> 6, lane = tid & 63, l15 = lane & 15, l4 = lane >> 4;
  const int T2 = 2 * T;
  const int nbt = tgx * BB;
  const int nbb = bgx * BB;
  const int bid = blockIdx.x;

  if (bid < nbt) {
    // ================= temporal part =================
    const int wg = (bid & 7) * (nbt >> 3) + (bid >> 3);  // XCD chunking
    const int bx = wg % tgx, b = wg / tgx;
    const int i0 = bx * 64 + wave * 16;
    const int myti = i0 >> 4;
    const bool alive = myti < NTt;
    const short* zf = zfrag + (size_t)b * NTt * KST * 512;

    short8 af[KST];
#pragma unroll
    for (int ks = 0; ks < KST; ++ks) {
      af[ks] = (short8){0, 0, 0, 0, 0, 0, 0, 0};
      if (alive) af[ks] = *(const short8*)(zf + ((size_t)myti * KST + ks) * 512 + lane * 8);
    }
    const float Nb = bmax[b];
    float B[4], se[4];
    int ig[4]; bool dlane[4];
#pragma unroll
    for (int r = 0; r < 4; ++r) {
      ig[r] = i0 + l4 * 4 + r;
      int ix = ig[r] < T2 ? ig[r] : T2 - 1;
      B[r] = fmaxf(norms[(size_t)b * T2 + ix] * Nb * LOG2E - 110.f, 0.f);
      se[r] = 0.f;
      dlane[r] = (l15 == l4 * 4 + r);
    }

    auto proc = [&](int ct, f32x4 d) {
      if (alive && ct == myti) {
#pragma unroll
        for (int r = 0; r < 4; ++r)
          se[r] += dlane[r] ? 0.f : EXP2F(fmaf(d[r], LOG2E, -B[r]));
      } else {
#pragma unroll
        for (int r = 0; r < 4; ++r)
          se[r] += EXP2F(fmaf(d[r], LOG2E, -B[r]));
      }
    };

    int ct = 0;
    for (; ct + UNR - 1 < NTt; ct += UNR) {
      short8 bb[UNR][KST];
#pragma unroll
      for (int u = 0; u < UNR; ++u)
#pragma unroll
        for (int ks = 0; ks < KST; ++ks)
          bb[u][ks] = *(const short8*)(zf + ((size_t)(ct + u) * KST + ks) * 512 + lane * 8);
      f32x4 dd[UNR];
#pragma unroll
      for (int u = 0; u < UNR; ++u) {
        dd[u] = (f32x4){0.f, 0.f, 0.f, 0.f};
#pragma unroll
        for (int ks = 0; ks < KST; ++ks)
          dd[u] = __builtin_amdgcn_mfma_f32_16x16x32_bf16(af[ks], bb[u][ks], dd[u], 0, 0, 0);
      }
#pragma unroll
      for (int u = 0; u < UNR; ++u) proc(ct + u, dd[u]);
    }
    for (; ct < NTt; ++ct) {
      short8 b0[KST];
#pragma unroll
      for (int ks = 0; ks < KST; ++ks)
        b0[ks] = *(const short8*)(zf + ((size_t)ct * KST + ks) * 512 + lane * 8);
      f32x4 d0 = {0.f, 0.f, 0.f, 0.f};
#pragma unroll
      for (int ks = 0; ks < KST; ++ks)
        d0 = __builtin_amdgcn_mfma_f32_16x16x32_bf16(af[ks], b0[ks], d0, 0, 0, 0);
      proc(ct, d0);
    }

    const float npad = (float)(NTt * 16 - T2);
    float tot = 0.f;
#pragma unroll
    for (int r = 0; r < 4; ++r) {
      float sv = se[r];
#pragma unroll
      for (int off = 1; off < 16; off <<= 1) sv += __shfl_xor(sv, off);
      sv -= npad * EXP2F(-B[r]);
      if (l15 == 0 && ig[r] < T2) {
        int ii = ig[r] < T ? ig[r] : ig[r] - T;
        float lse = (__log2f(fmaxf(sv, 1e-37f)) + B[r]) * LN2;
        tot += roww[ii] * lse;
      }
    }
    block_acc256(tot, scale, acc);

  } else if (bid < nbt + nbb) {
    // ================= band part =================
    const int r2 = bid - nbt;
    const int wg = (r2 & 7) * (nbb >> 3) + (r2 >> 3);    // XCD chunking
    const int bx = wg % bgx, b = wg / bgx;
    const int ii0 = bx * 64;
    float* Y = (float*)smem;                              // [78][C+1]
    float* f = (float*)(smem + 78 * (C + 1) * 4);         // [8]
    if (tid < 8) f[tid] = ftab[tid];
    const __hip_bfloat16* zbb = zb + (size_t)b * T2 * C;
    for (int idx = tid; idx < 78 * (C / 8); idx += 256) {
      int rr = idx / (C / 8), k = (idx % (C / 8)) * 8;
      int ii = ii0 - 7 + rr;
      if (ii >= 0 && ii < T) {
        short8 v1 = *(const short8*)(zbb + (size_t)ii * C + k);
        short8 v2 = *(const short8*)(zbb + (size_t)(T + ii) * C + k);
#pragma unroll
        for (int e = 0; e < 8; ++e) Y[rr * (C + 1) + k + e] = bfb2f(v1[e]) + bfb2f(v2[e]);
      } else {
#pragma unroll
        for (int e = 0; e < 8; ++e) Y[rr * (C + 1) + k + e] = 0.f;
      }
    }
    float p2 = 0.f;
    for (int idx = tid; idx < 64 * (C / 8); idx += 256) {
      int rr = idx / (C / 8), k = (idx % (C / 8)) * 8;
      int ii = ii0 + rr;
      if (ii < T) {
        short8 v1 = *(const short8*)(zbb + (size_t)ii * C + k);
        short8 v2 = *(const short8*)(zbb + (size_t)(T + ii) * C + k);
#pragma unroll
        for (int e = 0; e < 8; ++e) {
          float f1 = bfb2f(v1[e]), f2 = bfb2f(v2[e]);
          p2 = fmaf(f1, f1, p2); p2 = fmaf(f2, f2, p2);
        }
      }
    }
    __syncthreads();
    const int m = tid & 63, q = tid >> 6;
    float p = 0.f;
    if (ii0 + m < T) {
      int rr = m + 7;
      constexpr int SL = C / 4;
      for (int k = q * SL; k < (q + 1) * SL; ++k) {
        float g = f[0] * Y[rr * (C + 1) + k];
#pragma unroll
        for (int dd = 1; dd < 8; ++dd)
          g = fmaf(f[dd], Y[(rr - dd) * (C + 1) + k] + Y[(rr + dd) * (C + 1) + k], g);
        p = fmaf(Y[rr * (C + 1) + k], g, p);
      }
    }
    block_acc256(f[0] * p2 - p, scale, acc);

  } else {
    // ================= instance part (sl from global) =================
    const int t = bid - nbt - nbb;
    char* rz = smem;                                        // 256*C bytes
    float* normsh = (float*)(smem + 256 * C);               // [128]
    float* pmx = (float*)(smem + 256 * C + 512);            // [4]
    for (int idx = tid; idx < 128 * (C / 8); idx += 256) {
      int ln = idx & 63;
      int ks = (idx >> 6) & (KST - 1);
      int t16 = idx >> (6 + LOGK);
      int r = t16 * 16 + (ln & 15);
      size_t grow = (size_t)(r & 63) * T2 + ((r < 64) ? t : T + t);
      *(short8*)(rz + (size_t)idx * 16) = *(const short8*)(zb + grow * C + ks * 32 + (ln >> 4) * 8);
    }
    if (tid < 128) normsh[tid] = norms[(size_t)(tid & 63) * T2 + ((tid < 64) ? t : T + t)];
    __syncthreads();
    float nv = (tid < 128) ? normsh[tid] : 0.f;
#pragma unroll
    for (int off = 32; off; off >>= 1) nv = fmaxf(nv, __shfl_xor(nv, off));
    if (lane == 0) pmx[wave] = nv;
    __syncthreads();
    const float Nt = fmaxf(fmaxf(pmx[0], pmx[1]), fmaxf(pmx[2], pmx[3]));

    short8 af[2][KST];
#pragma unroll
    for (int rt = 0; rt < 2; ++rt)
#pragma unroll
      for (int ks = 0; ks < KST; ++ks)
        af[rt][ks] = *(const short8*)(rz + ((((wave * 2 + rt) * KST + ks) << 10) | (lane << 4)));
    float B[2][4], se[2][4], w4[2][4][4];
    int bi2[2][4]; bool dlane[4];
#pragma unroll
    for (int r = 0; r < 4; ++r) dlane[r] = (l15 == l4 * 4 + r);
#pragma unroll
    for (int rt = 0; rt < 2; ++rt)
#pragma unroll
      for (int r = 0; r < 4; ++r) {
        int igv = wave * 32 + rt * 16 + l4 * 4 + r;
        int bi = igv & 63;
        B[rt][r] = fmaxf(normsh[igv] * Nt * LOG2E - 110.f, 0.f);
        se[rt][r] = 0.f;
        bi2[rt][r] = bi;
#pragma unroll
        for (int c4 = 0; c4 < 4; ++c4) w4[rt][r][c4] = sl[bi * 64 + ((l15 + 16 * c4) & 63)];
      }
    float wdot = 0.f;

#pragma unroll
    for (int rt = 0; rt < 2; ++rt) {
      int ri0 = wave * 32 + rt * 16;
#pragma unroll
      for (int ct = 0; ct < 8; ++ct) {
        f32x4 d = {0.f, 0.f, 0.f, 0.f};
#pragma unroll
        for (int ks = 0; ks < KST; ++ks) {
          short8 bv = *(const short8*)(rz + (((ct * KST + ks) << 10) | (lane << 4)));
          d = __builtin_amdgcn_mfma_f32_16x16x32_bf16(af[rt][ks], bv, d, 0, 0, 0);
        }
        if (ri0 == ct * 16) {
#pragma unroll
          for (int r = 0; r < 4; ++r) {
            float dv = d[r];
            se[rt][r] += dlane[r] ? 0.f : EXP2F(fmaf(dv, LOG2E, -B[rt][r]));
            wdot = fmaf(dlane[r] ? 0.f : w4[rt][r][ct & 3], dv, wdot);
          }
        } else {
#pragma unroll
          for (int r = 0; r < 4; ++r) {
            float dv = d[r];
            se[rt][r] += EXP2F(fmaf(dv, LOG2E, -B[rt][r]));
            wdot = fmaf(w4[rt][r][ct & 3], dv, wdot);
          }
        }
      }
    }
    float tot = -wdot;
#pragma unroll
    for (int rt = 0; rt < 2; ++rt)
#pragma unroll
      for (int r = 0; r < 4; ++r) {
        float sv = se[rt][r];
#pragma unroll
        for (int off = 1; off < 16; off <<= 1) sv += __shfl_xor(sv, off);
        if (l15 == 0) {
          int bi = bi2[rt][r];
          float rw = 2.f * slrs[bi] - sl[bi * 64 + bi];
          float lse = (__log2f(fmaxf(sv, 1e-37f)) + B[rt][r]) * LN2;
          tot += rw * lse;
        }
      }
    block_acc256(tot, scale, acc);
  }
}

// final FC (both sides) + loss finalize (block 0)
__global__ void fc2_k(const float* __restrict__ A1, const float* __restrict__ A2,
                      const float* __restrict__ wf, const float* __restrict__ bf,
                      float* __restrict__ lg1, float* __restrict__ lg2,
                      const double* __restrict__ acc, float* __restrict__ out_loss) {
  int n = blockIdx.x & 63;
  int side = blockIdx.x >> 6;
  const float* a = side ? A2 : A1;
  float* lg = side ? lg2 : lg1;
  float accv[5] = {0.f, 0.f, 0.f, 0.f, 0.f};
  for (int f = threadIdx.x; f < 16640; f += 1024) {
    float av = a[(size_t)n * 16640 + f];
    const float* wr = wf + (size_t)f * 5;
#pragma unroll
    for (int k = 0; k < 5; ++k) accv[k] = fmaf(av, wr[k], accv[k]);
  }
  __shared__ float red[16][5];
#pragma unroll
  for (int k = 0; k < 5; ++k) {
    float v = accv[k];
#pragma unroll
    for (int off = 32; off; off >>= 1) v += __shfl_down(v, off);
    if ((threadIdx.x & 63) == 0) red[threadIdx.x >> 6][k] = v;
  }
  __syncthreads();
  if (threadIdx.x == 0) {
#pragma unroll
    for (int k = 0; k < 5; ++k) {
      float s = bf[k];
#pragma unroll
      for (int i = 0; i < 16; ++i) s += red[i][k];
      lg[n * 5 + k] = s;
    }
    if (blockIdx.x == 0) *out_loss = (float)(*acc);
  }
}

extern "C" void kernel_launch(void* const* d_in, const int* in_sizes, int n_in,
                              void* d_out, int out_size, void* d_ws, size_t ws_size,
                              hipStream_t stream) {
  const float* aug1 = (const float*)d_in[0];
  const float* aug2 = (const float*)d_in[1];
  const float* sl = (const float*)d_in[2];
  const float* wconv[3] = {(const float*)d_in[3], (const float*)d_in[6], (const float*)d_in[9]};
  const float* gam[3]   = {(const float*)d_in[4], (const float*)d_in[7], (const float*)d_in[10]};
  const float* bet[3]   = {(const float*)d_in[5], (const float*)d_in[8], (const float*)d_in[11]};
  const float* wf = (const float*)d_in[12];
  const float* bf = (const float*)d_in[13];
  float* out = (float*)d_out;
  float* ws = (float*)d_ws;
  if (ws_size < (size_t)WS_TOTAL * sizeof(float)) return;

  double* acc = (double*)(ws + WS_ACC);
  float* bnA = ws + WS_BNA;
  float* bnB = ws + WS_BNB;
  float* ftab = ws + WS_FTAB;
  float* roww = ws + WS_ROWW;
  float* slrs = ws + WS_SLRS;
  short* wbf[3] = {(short*)(ws + WS_WBF1), (short*)(ws + WS_WBF2), (short*)(ws + WS_WBF3)};
  float* partS = ws + WS_PART1;
  float* partS2 = ws + WS_PART2;
  float* normsP = ws + WS_NORMS;
  float* bmaxP = ws + WS_BMAX;
  short* xpad = (short*)(ws + WS_XPAD);
  short* convb = (short*)(ws + WS_CONV);
  __hip_bfloat16* zb16 = (__hip_bfloat16*)(ws + WS_ZB16);
  short* zfragP = (short*)(ws + WS_ZFRAG);

  const int Lc[3]    = {1025, 514, 259};
  const int Lcp[3]   = {1028, 516, 260};
  const int Cout[3]  = {32, 64, 128};
  const int Tarr[3]  = {513, 258, 130};
  const float sig[3] = {2.f, 4.f, 8.f};

  float* A1 = out + O_A1;
  float* A2 = out + O_A2;

  prep_k<<<457, 256, 0, stream>>>(acc, sl, slrs, wconv[0], wconv[1], wconv[2],
                                  wbf[0], wbf[1], wbf[2], aug1, aug2, xpad);

  for (int d = 0; d < 3; ++d) {
    int T = Tarr[d];
    int T2 = 2 * T;
    int jt = (Lc[d] + 63) / 64;
    int NTt = (T2 + 15) >> 4;

    switch (d) {
      case 0: conv4_k<1, 8, 32, 1, 1032, 24><<<dim3(jt, 128, 1), 256, 0, stream>>>(xpad, wbf[0], convb, partS, partS2, Lc[d], Lcp[d]); break;
      case 1: conv4_k<32, 32, 64, 1, 528, 40><<<dim3(jt, 128, 1), 256, 0, stream>>>(xpad, wbf[1], convb, partS, partS2, Lc[d], Lcp[d]); break;
      default: conv4_k<64, 64, 128, 4, 272, 72><<<dim3(jt, 128, 4), 256, 0, stream>>>(xpad, wbf[2], convb, partS, partS2, Lc[d], Lcp[d]); break;
    }
    stats2_k<<<2 * Cout[d], 256, 0, stream>>>(partS, partS2, gam[d], bet[d], bnA, bnB, 64 * jt, BB * Lc[d], Cout[d]);
    {
      float* p1 = (d == 2) ? A1 : nullptr;
      float* p2 = (d == 2) ? A2 : nullptr;
      short* xn = (d == 2) ? nullptr : xpad;
      int TPn = (d == 0) ? 528 : (d == 1) ? 272 : 0;
      pool3_k<<<dim3((T + 31) / 32, Cout[d] / 32, 128), dim3(32, 8), 0, stream>>>(
          convb, bnA, bnB, p1, p2, zb16, zfragP, NTt, xn, TPn, Cout[d], Lc[d], Lcp[d], T);
    }

    double scale = 0.5 / (128.0 * (double)T);
    int tgx = (T2 + 63) / 64;
    int bgx = (T + 63) / 64;
    int nblk = tgx * BB + bgx * BB + T;
    switch (d) {
      case 0:
        norms_k<32><<<64, 1024, 0, stream>>>(zb16, normsP, bmaxP, zfragP, NTt, ftab, roww, T, sig[d]);
        loss_k<32><<<nblk, 256, 0, stream>>>(zfragP, zb16, ftab, roww, normsP, bmaxP, sl, slrs, T, NTt, tgx, bgx, scale, acc);
        break;
      case 1:
        norms_k<64><<<64, 1024, 0, stream>>>(zb16, normsP, bmaxP, zfragP, NTt, ftab, roww, T, sig[d]);
        loss_k<64><<<nblk, 256, 0, stream>>>(zfragP, zb16, ftab, roww, normsP, bmaxP, sl, slrs, T, NTt, tgx, bgx, scale, acc);
        break;
      default:
        norms_k<128><<<64, 1024, 0, stream>>>(zb16, normsP, bmaxP, zfragP, NTt, ftab, roww, T, sig[d]);
        loss_k<128><<<nblk, 256, 0, stream>>>(zfragP, zb16, ftab, roww, normsP, bmaxP, sl, slrs, T, NTt, tgx, bgx, scale, acc);
        break;
    }
  }
  fc2_k<<<128, 1024, 0, stream>>>(A1, A2, wf, bf, out + O_LG1, out + O_LG2, acc, out + O_LOSS);
}

// Round 21
// 205.845 us; speedup vs baseline: 1.0156x; 1.0156x over previous
//
#include <hip/hip_runtime.h>
#include <hip/hip_bf16.h>
#include <math.h>

#define BB 64
#define PB_STRIDE 1536      // >= 64 b * 17 jtiles
#define CONV_SIDE 2129920   // bf16 elems per side (64*128*260 max)

typedef __attribute__((ext_vector_type(8))) short short8;
typedef __attribute__((ext_vector_type(4))) short short4v;
typedef __attribute__((ext_vector_type(4))) float f32x4;

// workspace layout (floats)
#define WS_ACC    0
#define WS_BNA    8
#define WS_BNB    264
#define WS_FTAB   520
#define WS_ROWW   536
#define WS_SLRS   1064
#define WS_WBF1   1128     // 1024 shorts (32 o x 64 K)
#define WS_WBF2   2152     // 16384 shorts
#define WS_WBF3   10344    // 65536 shorts
#define WS_PART1  43112    // 393216
#define WS_PART2  436328   // 393216
#define WS_NORMS  829544   // 66560
#define WS_BMAX   896104   // 64
#define WS_XPAD   896168   // 2228224 floats padded bf16 conv inputs
#define WS_CONV   3124392  // 2129920 floats = 2 sides x CONV_SIDE bf16
#define WS_ZB16   5254312  // 1100000
#define WS_ZFRAG  6354312  // 1120000 floats (fragment-packed z)
#define WS_TOTAL  7474312

// d_out layout (floats)
#define O_LG1  0
#define O_LG2  320
#define O_A1   640
#define O_A2   (640 + 1064960)
#define O_LOSS (O_A2 + 1064960)

#define LOG2E 1.44269504f
#define LN2   0.69314718f

// hardware v_exp_f32: exact enough on our guaranteed arg range [-222, 110]
#define EXP2F(x) __builtin_amdgcn_exp2f(x)

__device__ __forceinline__ short f2bf(float f) {
  unsigned u = __float_as_uint(f);
  u += 0x7FFFu + ((u >> 16) & 1u);
  return (short)(u >> 16);
}
__device__ __forceinline__ float bfb2f(short s) {
  return __uint_as_float(((unsigned)(unsigned short)s) << 16);
}

// ---------- fused prep: init + all weight preps + aug pad (grid 457) ----------
__global__ void prep_k(double* acc, const float* __restrict__ sl, float* __restrict__ slrs,
                       const float* __restrict__ w1, const float* __restrict__ w2,
                       const float* __restrict__ w3, short* __restrict__ o1,
                       short* __restrict__ o2, short* __restrict__ o3,
                       const float* __restrict__ a1, const float* __restrict__ a2,
                       short* __restrict__ xp) {
  int bid = blockIdx.x;
  if (bid == 0) {
    if (threadIdx.x == 0) *acc = 0.0;
    if (threadIdx.x < 64) {
      int r = threadIdx.x;
      float s = 0.f;
      for (int c = 0; c < 64; ++c) s += sl[r * 64 + c];
      slrs[r] = s;
    }
    return;
  }
  if (bid <= 328) {
    int i = (bid - 1) * 256 + threadIdx.x;
    const float* w; short* ob; int CIN, CIPAD;
    if (i < 2048)        { w = w1; ob = o1; CIN = 1;  CIPAD = 8; }
    else if (i < 18432)  { i -= 2048;  w = w2; ob = o2; CIN = 32; CIPAD = 32; }
    else                 { i -= 18432; w = w3; ob = o3; CIN = 64; CIPAD = 64; }
    int KTOT = CIPAD * 8;
    int o = i / KTOT, q = i - o * KTOT;
    int k = q / CIPAD, ci = q - k * CIPAD;
    short v = 0;
    if (ci < CIN) v = f2bf(w[(o * CIN + ci) * 8 + k]);
    ob[i] = v;
    return;
  }
  int sb = bid - 329;
  int side = sb >> 6, b = sb & 63;
  const float* src = (side ? a2 : a1) + (size_t)b * 1024;
  short* dst = xp + (size_t)sb * 1032;
  for (int e = threadIdx.x; e < 1032; e += 256) {
    short v = 0;
    if (e >= 4 && e < 1028) v = f2bf(src[e - 4]);
    dst[e] = v;
  }
}

// ---------- K-permuted MFMA conv1d, weights staged to LDS (swizzled) ----------
template <int CIN, int CIPAD, int COUT, int OSPLIT, int XP, int LRS>
__launch_bounds__(256)
__global__ void conv4_k(const short* __restrict__ xbf, const short* __restrict__ wbf,
                        short* __restrict__ ybf, float* __restrict__ part_s,
                        float* __restrict__ part_s2, int Lc, int Lcp) {
  constexpr int KTOT = CIPAD * 8;
  constexpr int S = KTOT / 32;
  constexpr int COS = COUT / OSPLIT;
  constexpr int NT = COS / 16;
  constexpr int RSd = LRS / 2;
  constexpr int CP2 = CIPAD / 2;
  __shared__ __attribute__((aligned(16))) unsigned traw[72 * RSd];
  __shared__ __attribute__((aligned(16))) char wlds[COS * KTOT * 2];
  __shared__ float ps[4][COS], ps2[4][COS];
  const int tid = threadIdx.x;
  const int wave = tid >> 6, lane = tid & 63, l15 = lane & 15, l4 = lane >> 4;
  const int by = blockIdx.y;
  const int b = by & 63, side = by >> 6;
  const int o0 = blockIdx.z * COS;
  const int j0 = blockIdx.x * 64;
  const short* xb = xbf + (size_t)(side * 64 + b) * CIN * XP;
  short* yside = ybf + (size_t)side * CONV_SIDE;

  for (int idx = tid; idx < COS * (KTOT / 8); idx += 256) {
    int o = idx / (KTOT / 8);
    int q8 = idx - o * (KTOT / 8);
    short8 wv = *(const short8*)(wbf + (size_t)(o0 + o) * KTOT + q8 * 8);
    unsigned byte = (unsigned)((o * KTOT + q8 * 8) * 2) ^ (unsigned)((o & 7) << 4);
    *(short8*)(wlds + byte) = wv;
  }
  for (int idx = tid; idx < 9 * CP2; idx += 256) {
    int cp = idx & (CP2 - 1);
    int u = idx / CP2;
    int ci = cp * 2;
    short8 av = (short8){0, 0, 0, 0, 0, 0, 0, 0};
    short8 bv = (short8){0, 0, 0, 0, 0, 0, 0, 0};
    if (ci < CIN)     av = *(const short8*)(xb + (size_t)ci * XP + j0 + u * 8);
    if (ci + 1 < CIN) bv = *(const short8*)(xb + (size_t)(ci + 1) * XP + j0 + u * 8);
#pragma unroll
    for (int t = 0; t < 8; ++t)
      traw[(u * 8 + t) * RSd + cp] =
        ((unsigned)(unsigned short)av[t]) | (((unsigned)(unsigned short)bv[t]) << 16);
  }
  __syncthreads();

  f32x4 acc[NT];
#pragma unroll
  for (int nt = 0; nt < NT; ++nt) acc[nt] = (f32x4){0.f, 0.f, 0.f, 0.f};

  const int row = wave * 16 + l15;
  const unsigned wsw = (unsigned)((l15 & 7) << 4);
#pragma unroll
  for (int s = 0; s < S; ++s) {
    int k, cd;
    if (CIPAD == 8)       { k = s * 4 + l4; cd = 0; }
    else if (CIPAD == 32) { k = s;          cd = l4 * 4; }
    else                  { k = s >> 1;     cd = (s & 1) * 16 + l4 * 4; }
    short8 af = *(const short8*)(traw + (row + k) * RSd + cd);
#pragma unroll
    for (int nt = 0; nt < NT; ++nt) {
      unsigned wbyte = (unsigned)(((nt * 16 + l15) * KTOT + s * 32 + l4 * 8) * 2) ^ wsw;
      short8 wv = *(const short8*)(wlds + wbyte);
      acc[nt] = __builtin_amdgcn_mfma_f32_16x16x32_bf16(af, wv, acc[nt], 0, 0, 0);
    }
  }

  const int jbase = j0 + wave * 16 + l4 * 4;
#pragma unroll
  for (int nt = 0; nt < NT; ++nt) {
    int ol = nt * 16 + l15;
    size_t orow = ((size_t)b * COUT + (o0 + ol)) * Lcp;
    float s = 0.f, s2 = 0.f;
    if (jbase + 3 < Lc) {
      short4v sv = (short4v){f2bf(acc[nt][0]), f2bf(acc[nt][1]), f2bf(acc[nt][2]), f2bf(acc[nt][3])};
      *(short4v*)(yside + orow + jbase) = sv;
#pragma unroll
      for (int r = 0; r < 4; ++r) { float v = acc[nt][r]; s += v; s2 = fmaf(v, v, s2); }
    } else {
#pragma unroll
      for (int r = 0; r < 4; ++r) {
        if (jbase + r < Lc) {
          float v = acc[nt][r];
          yside[orow + jbase + r] = f2bf(v);
          s += v; s2 = fmaf(v, v, s2);
        }
      }
    }
    s  += __shfl_xor(s, 16);  s  += __shfl_xor(s, 32);
    s2 += __shfl_xor(s2, 16); s2 += __shfl_xor(s2, 32);
    if (lane < 16) { ps[wave][ol] = s; ps2[wave][ol] = s2; }
  }
  __syncthreads();
  int blk = b * gridDim.x + blockIdx.x;
  for (int o = tid; o < COS; o += 256) {
    size_t pi = (size_t)(side * COUT + o0 + o) * PB_STRIDE + blk;
    part_s [pi] = ps[0][o] + ps[1][o] + ps[2][o] + ps[3][o];
    part_s2[pi] = ps2[0][o] + ps2[1][o] + ps2[2][o] + ps2[3][o];
  }
}

// reduce conv partials -> bnA/bnB per (side, channel)
__global__ void stats2_k(const float* __restrict__ part_s, const float* __restrict__ part_s2,
                         const float* __restrict__ g, const float* __restrict__ beta,
                         float* __restrict__ bnA, float* __restrict__ bnB,
                         int nblk, int n, int COUT) {
  int bid = blockIdx.x;
  int c = bid % COUT;
  float s = 0.f, s2 = 0.f;
  for (int i = threadIdx.x; i < nblk; i += 256) {
    s += part_s[(size_t)bid * PB_STRIDE + i];
    s2 += part_s2[(size_t)bid * PB_STRIDE + i];
  }
#pragma unroll
  for (int off = 32; off; off >>= 1) { s += __shfl_down(s, off); s2 += __shfl_down(s2, off); }
  __shared__ float as[4], as2[4];
  if ((threadIdx.x & 63) == 0) { as[threadIdx.x >> 6] = s; as2[threadIdx.x >> 6] = s2; }
  __syncthreads();
  if (threadIdx.x == 0) {
    float S = as[0] + as[1] + as[2] + as[3];
    float S2 = as2[0] + as2[1] + as2[2] + as2[3];
    float fn = (float)n;
    float mu = S / fn;
    float var = S2 / fn - mu * mu;
    float A = g[c] * rsqrtf(var + 1e-5f);
    bnA[bid] = A;
    bnB[bid] = beta[c] - mu * A;
  }
}

// fused-sides BN-apply + ReLU + maxpool; writes zb, zfrag, optional pooled / next input
__global__ void pool3_k(const short* __restrict__ convb, const float* __restrict__ bnA,
                        const float* __restrict__ bnB, float* __restrict__ pd1,
                        float* __restrict__ pd2, __hip_bfloat16* __restrict__ zb,
                        short* __restrict__ zfrag, int NTt,
                        short* __restrict__ xnext, int TPn,
                        int C, int Lc, int Lcp, int Tout) {
  __shared__ float tile[32][33];
  int bz = blockIdx.z;
  int b = bz & 63, side = bz >> 6;
  const short* cs = convb + (size_t)side * CONV_SIDE;
  float* pooled = side ? pd2 : pd1;
  int zoff = side * Tout;
  int c0 = blockIdx.y * 32;
  int t0 = blockIdx.x * 32;
  int tx = threadIdx.x;
  int ty = threadIdx.y;
  int tid = ty * 32 + tx;
#pragma unroll
  for (int q = 0; q < 4; ++q) {
    int c = c0 + ty + q * 8;
    int t = t0 + tx;
    size_t xrow = xnext ? ((size_t)(side * 64 + b) * C + c) * TPn : 0;
    float v = 0.f;
    if (t < Tout) {
      const short* row = cs + ((size_t)b * C + c) * Lcp;
      float A = bnA[side * C + c], Bb = bnB[side * C + c];
      v = -3.0e38f;
      int p0 = 2 * t - 1;
      if (p0 >= 0) v = fmaxf(v, fmaxf(fmaf(A, bfb2f(row[p0]), Bb), 0.f));
      int p1 = 2 * t;
      if (p1 < Lc) v = fmaxf(v, fmaxf(fmaf(A, bfb2f(row[p1]), Bb), 0.f));
      if (pooled) pooled[((size_t)b * C + c) * Tout + t] = v;
      if (xnext) xnext[xrow + 4 + t] = f2bf(v);
    } else if (xnext && 4 + t < TPn) {
      xnext[xrow + 4 + t] = 0;
    }
    if (xnext && t0 == 0 && tx < 4) xnext[xrow + tx] = 0;
    tile[ty + q * 8][tx] = v;   // tile[c-off][t-off]
  }
  __syncthreads();
  int T2 = 2 * Tout;
#pragma unroll
  for (int q = 0; q < 4; ++q) {
    int t = t0 + ty + q * 8;
    int c = c0 + tx;
    if (t < Tout)
      zb[((size_t)b * T2 + zoff + t) * (size_t)C + c] = __float2bfloat16(tile[tx][ty + q * 8]);
  }
  if (tid < 128) {
    int t_off = tid & 31, cg = tid >> 5;
    if (t0 + t_off < Tout) {
      short8 v;
#pragma unroll
      for (int e = 0; e < 8; ++e) v[e] = f2bf(tile[cg * 8 + e][t_off]);
      int r = zoff + t0 + t_off;
      int ct = r >> 4, l15r = r & 15;
      int ch = c0 + cg * 8;
      int KST = C >> 5;
      int ks = ch >> 5, g4 = (ch >> 3) & 3;
      int lane2 = l15r + (g4 << 4);
      *(short8*)(zfrag + (((size_t)b * NTt + ct) * (size_t)KST + ks) * 512 + (size_t)lane2 * 8) = v;
    }
  }
}

// per-row norms + batch max; block 0 computes ftab/roww; each block zeroes zfrag pad
template <int C>
__global__ void norms_k(const __hip_bfloat16* __restrict__ zb, float* __restrict__ norms,
                        float* __restrict__ bmax, short* __restrict__ zfrag, int NTt,
                        float* __restrict__ ftab, float* __restrict__ roww,
                        int T, float sigma) {
  constexpr int KST = C / 32;
  int b = blockIdx.x;
  int T2 = 2 * T;
  __shared__ float fs[8];
  if (threadIdx.x < 8) {
    double mm = 2.0 / (1.0 + exp((double)threadIdx.x * (double)sigma));
    float f = (mm < 1e-6) ? 0.f : (float)mm;
    fs[threadIdx.x] = f;
    if (b == 0) ftab[threadIdx.x] = f;
  }
  __syncthreads();
  if (b == 0) {
    for (int i = threadIdx.x; i < T; i += 1024) {
      float s = fs[0];
#pragma unroll
      for (int d = 1; d < 8; ++d) s += fs[d] * ((i >= d ? 1.f : 0.f) + (i + d < T ? 1.f : 0.f));
      roww[i] = 2.f * s - fs[0];
    }
  }
  int rem = T2 & 15;
  if (rem) {
    for (int u = threadIdx.x; u < KST * 64; u += 1024) {
      int ks = u >> 6, l = u & 63;
      if ((l & 15) >= rem)
        *(short8*)(zfrag + (((size_t)b * NTt + (NTt - 1)) * (size_t)KST + ks) * 512 + (size_t)l * 8) =
            (short8){0, 0, 0, 0, 0, 0, 0, 0};
    }
  }
  const __hip_bfloat16* zbb = zb + (size_t)b * T2 * C;
  int q = threadIdx.x & 3, r0 = threadIdx.x >> 2;
  float nm = 0.f;
  for (int r = r0; r < T2; r += 256) {
    float s = 0.f;
    const __hip_bfloat16* p = zbb + (size_t)r * C + q * (C / 4);
#pragma unroll
    for (int v = 0; v < C / 32; ++v) {
      short8 sv = *(const short8*)(p + v * 8);
#pragma unroll
      for (int e = 0; e < 8; ++e) { float f = bfb2f(sv[e]); s = fmaf(f, f, s); }
    }
    s += __shfl_xor(s, 1); s += __shfl_xor(s, 2);
    float nr = sqrtf(s);
    if (q == 0) norms[(size_t)b * T2 + r] = nr;
    nm = fmaxf(nm, nr);
  }
#pragma unroll
  for (int off = 32; off; off >>= 1) nm = fmaxf(nm, __shfl_xor(nm, off));
  __shared__ float pm[16];
  if ((threadIdx.x & 63) == 0) pm[threadIdx.x >> 6] = nm;
  __syncthreads();
  if (threadIdx.x == 0) {
    float m = 0.f;
#pragma unroll
    for (int i = 0; i < 16; ++i) m = fmaxf(m, pm[i]);
    bmax[b] = m;
  }
}

__device__ __forceinline__ void block_acc256(float v, double scale, double* acc) {
#pragma unroll
  for (int off = 32; off; off >>= 1) v += __shfl_down(v, off);
  __shared__ float part[4];
  if ((threadIdx.x & 63) == 0) part[threadIdx.x >> 6] = v;
  __syncthreads();
  if (threadIdx.x == 0)
    atomicAdd(acc, (double)(part[0] + part[1] + part[2] + part[3]) * scale);
}

// ---------- FUSED loss kernel: temporal (LDS-shared zfrag MFMA) | band | instance ----------
// Temporal: 4 waves share identical column fragments -> cooperatively stage 8KB chunks
// in LDS (contiguous copy, zero index math), then conflict-free ds_read_b128.
template <int C>
__launch_bounds__(256)
__global__ void loss_k(const short* __restrict__ zfrag, const __hip_bfloat16* __restrict__ zb,
                       const float* __restrict__ ftab, const float* __restrict__ roww,
                       const float* __restrict__ norms, const float* __restrict__ bmax,
                       const float* __restrict__ sl, const float* __restrict__ slrs,
                       int T, int NTt, int tgx, int bgx,
                       double scale, double* __restrict__ acc) {
  constexpr int KST = C / 32;
  constexpr int LOGK = (KST == 1) ? 0 : (KST == 2) ? 1 : 2;
  constexpr int CHT = 8 / KST;                 // tiles per 8KB LDS chunk
  constexpr int SB_BAND = (78 * (C + 1) + 8) * 4;
  constexpr int SB_INST = 256 * C + 128 * 4 + 16 + 16;
  constexpr int SB_TEMP = 8192;
  constexpr int SMEM0 = SB_BAND > SB_INST ? SB_BAND : SB_INST;
  constexpr int SMEM = SMEM0 > SB_TEMP ? SMEM0 : SB_TEMP;
  __shared__ __attribute__((aligned(16))) char smem[SMEM];
  const int tid = threadIdx.x;
  const int wave = tid >> 6, lane = tid & 63, l15 = lane & 15, l4 = lane >> 4;
  const int T2 = 2 * T;
  const int nbt = tgx * BB;
  const int nbb = bgx * BB;
  const int bid = blockIdx.x;

  if (bid < nbt) {
    // ================= temporal part =================
    const int wg = (bid & 7) * (nbt >> 3) + (bid >> 3);  // XCD chunking
    const int bx = wg % tgx, b = wg / tgx;
    const int i0 = bx * 64 + wave * 16;
    const int myti = i0 >> 4;
    const bool alive = myti < NTt;
    const short* zf = zfrag + (size_t)b * NTt * KST * 512;
    short8* sfrag = (short8*)smem;

    short8 af[KST];
#pragma unroll
    for (int ks = 0; ks < KST; ++ks) {
      af[ks] = (short8){0, 0, 0, 0, 0, 0, 0, 0};
      if (alive) af[ks] = *(const short8*)(zf + ((size_t)myti * KST + ks) * 512 + lane * 8);
    }
    const float Nb = bmax[b];
    float B[4], se[4];
    int ig[4]; bool dlane[4];
#pragma unroll
    for (int r = 0; r < 4; ++r) {
      ig[r] = i0 + l4 * 4 + r;
      int ix = ig[r] < T2 ? ig[r] : T2 - 1;
      B[r] = fmaxf(norms[(size_t)b * T2 + ix] * Nb * LOG2E - 110.f, 0.f);
      se[r] = 0.f;
      dlane[r] = (l15 == l4 * 4 + r);
    }

    auto proc = [&](int ct, f32x4 d) {
      if (alive && ct == myti) {
#pragma unroll
        for (int r = 0; r < 4; ++r)
          se[r] += dlane[r] ? 0.f : EXP2F(fmaf(d[r], LOG2E, -B[r]));
      } else {
#pragma unroll
        for (int r = 0; r < 4; ++r)
          se[r] += EXP2F(fmaf(d[r], LOG2E, -B[r]));
      }
    };

    for (int ct0 = 0; ct0 < NTt; ct0 += CHT) {
      int ntile = NTt - ct0;
      if (ntile > CHT) ntile = CHT;
      __syncthreads();
      // contiguous cooperative stage: ntile*KST*64 x short8
      const short8* src = (const short8*)(zf + (size_t)ct0 * KST * 512);
      for (int i = tid; i < ntile * KST * 64; i += 256) sfrag[i] = src[i];
      __syncthreads();
      for (int u = 0; u < ntile; ++u) {
        short8 bv[KST];
#pragma unroll
        for (int ks = 0; ks < KST; ++ks) bv[ks] = sfrag[(u * KST + ks) * 64 + lane];
        f32x4 d = {0.f, 0.f, 0.f, 0.f};
#pragma unroll
        for (int ks = 0; ks < KST; ++ks)
          d = __builtin_amdgcn_mfma_f32_16x16x32_bf16(af[ks], bv[ks], d, 0, 0, 0);
        proc(ct0 + u, d);
      }
    }

    const float npad = (float)(NTt * 16 - T2);
    float tot = 0.f;
#pragma unroll
    for (int r = 0; r < 4; ++r) {
      float sv = se[r];
#pragma unroll
      for (int off = 1; off < 16; off <<= 1) sv += __shfl_xor(sv, off);
      sv -= npad * EXP2F(-B[r]);
      if (l15 == 0 && ig[r] < T2) {
        int ii = ig[r] < T ? ig[r] : ig[r] - T;
        float lse = (__log2f(fmaxf(sv, 1e-37f)) + B[r]) * LN2;
        tot += roww[ii] * lse;
      }
    }
    block_acc256(tot, scale, acc);

  } else if (bid < nbt + nbb) {
    // ================= band part =================
    const int r2 = bid - nbt;
    const int wg = (r2 & 7) * (nbb >> 3) + (r2 >> 3);    // XCD chunking
    const int bx = wg % bgx, b = wg / bgx;
    const int ii0 = bx * 64;
    float* Y = (float*)smem;                              // [78][C+1]
    float* f = (float*)(smem + 78 * (C + 1) * 4);         // [8]
    if (tid < 8) f[tid] = ftab[tid];
    const __hip_bfloat16* zbb = zb + (size_t)b * T2 * C;
    for (int idx = tid; idx < 78 * (C / 8); idx += 256) {
      int rr = idx / (C / 8), k = (idx % (C / 8)) * 8;
      int ii = ii0 - 7 + rr;
      if (ii >= 0 && ii < T) {
        short8 v1 = *(const short8*)(zbb + (size_t)ii * C + k);
        short8 v2 = *(const short8*)(zbb + (size_t)(T + ii) * C + k);
#pragma unroll
        for (int e = 0; e < 8; ++e) Y[rr * (C + 1) + k + e] = bfb2f(v1[e]) + bfb2f(v2[e]);
      } else {
#pragma unroll
        for (int e = 0; e < 8; ++e) Y[rr * (C + 1) + k + e] = 0.f;
      }
    }
    float p2 = 0.f;
    for (int idx = tid; idx < 64 * (C / 8); idx += 256) {
      int rr = idx / (C / 8), k = (idx % (C / 8)) * 8;
      int ii = ii0 + rr;
      if (ii < T) {
        short8 v1 = *(const short8*)(zbb + (size_t)ii * C + k);
        short8 v2 = *(const short8*)(zbb + (size_t)(T + ii) * C + k);
#pragma unroll
        for (int e = 0; e < 8; ++e) {
          float f1 = bfb2f(v1[e]), f2 = bfb2f(v2[e]);
          p2 = fmaf(f1, f1, p2); p2 = fmaf(f2, f2, p2);
        }
      }
    }
    __syncthreads();
    const int m = tid & 63, q = tid >> 6;
    float p = 0.f;
    if (ii0 + m < T) {
      int rr = m + 7;
      constexpr int SL = C / 4;
      for (int k = q * SL; k < (q + 1) * SL; ++k) {
        float g = f[0] * Y[rr * (C + 1) + k];
#pragma unroll
        for (int dd = 1; dd < 8; ++dd)
          g = fmaf(f[dd], Y[(rr - dd) * (C + 1) + k] + Y[(rr + dd) * (C + 1) + k], g);
        p = fmaf(Y[rr * (C + 1) + k], g, p);
      }
    }
    block_acc256(f[0] * p2 - p, scale, acc);

  } else {
    // ================= instance part (sl from global) =================
    const int t = bid - nbt - nbb;
    char* rz = smem;                                        // 256*C bytes
    float* normsh = (float*)(smem + 256 * C);               // [128]
    float* pmx = (float*)(smem + 256 * C + 512);            // [4]
    for (int idx = tid; idx < 128 * (C / 8); idx += 256) {
      int ln = idx & 63;
      int ks = (idx >> 6) & (KST - 1);
      int t16 = idx >> (6 + LOGK);
      int r = t16 * 16 + (ln & 15);
      size_t grow = (size_t)(r & 63) * T2 + ((r < 64) ? t : T + t);
      *(short8*)(rz + (size_t)idx * 16) = *(const short8*)(zb + grow * C + ks * 32 + (ln >> 4) * 8);
    }
    if (tid < 128) normsh[tid] = norms[(size_t)(tid & 63) * T2 + ((tid < 64) ? t : T + t)];
    __syncthreads();
    float nv = (tid < 128) ? normsh[tid] : 0.f;
#pragma unroll
    for (int off = 32; off; off >>= 1) nv = fmaxf(nv, __shfl_xor(nv, off));
    if (lane == 0) pmx[wave] = nv;
    __syncthreads();
    const float Nt = fmaxf(fmaxf(pmx[0], pmx[1]), fmaxf(pmx[2], pmx[3]));

    short8 af[2][KST];
#pragma unroll
    for (int rt = 0; rt < 2; ++rt)
#pragma unroll
      for (int ks = 0; ks < KST; ++ks)
        af[rt][ks] = *(const short8*)(rz + ((((wave * 2 + rt) * KST + ks) << 10) | (lane << 4)));
    float B[2][4], se[2][4], w4[2][4][4];
    int bi2[2][4]; bool dlane[4];
#pragma unroll
    for (int r = 0; r < 4; ++r) dlane[r] = (l15 == l4 * 4 + r);
#pragma unroll
    for (int rt = 0; rt < 2; ++rt)
#pragma unroll
      for (int r = 0; r < 4; ++r) {
        int igv = wave * 32 + rt * 16 + l4 * 4 + r;
        int bi = igv & 63;
        B[rt][r] = fmaxf(normsh[igv] * Nt * LOG2E - 110.f, 0.f);
        se[rt][r] = 0.f;
        bi2[rt][r] = bi;
#pragma unroll
        for (int c4 = 0; c4 < 4; ++c4) w4[rt][r][c4] = sl[bi * 64 + ((l15 + 16 * c4) & 63)];
      }
    float wdot = 0.f;

#pragma unroll
    for (int rt = 0; rt < 2; ++rt) {
      int ri0 = wave * 32 + rt * 16;
#pragma unroll
      for (int ct = 0; ct < 8; ++ct) {
        f32x4 d = {0.f, 0.f, 0.f, 0.f};
#pragma unroll
        for (int ks = 0; ks < KST; ++ks) {
          short8 bv = *(const short8*)(rz + (((ct * KST + ks) << 10) | (lane << 4)));
          d = __builtin_amdgcn_mfma_f32_16x16x32_bf16(af[rt][ks], bv, d, 0, 0, 0);
        }
        if (ri0 == ct * 16) {
#pragma unroll
          for (int r = 0; r < 4; ++r) {
            float dv = d[r];
            se[rt][r] += dlane[r] ? 0.f : EXP2F(fmaf(dv, LOG2E, -B[rt][r]));
            wdot = fmaf(dlane[r] ? 0.f : w4[rt][r][ct & 3], dv, wdot);
          }
        } else {
#pragma unroll
          for (int r = 0; r < 4; ++r) {
            float dv = d[r];
            se[rt][r] += EXP2F(fmaf(dv, LOG2E, -B[rt][r]));
            wdot = fmaf(w4[rt][r][ct & 3], dv, wdot);
          }
        }
      }
    }
    float tot = -wdot;
#pragma unroll
    for (int rt = 0; rt < 2; ++rt)
#pragma unroll
      for (int r = 0; r < 4; ++r) {
        float sv = se[rt][r];
#pragma unroll
        for (int off = 1; off < 16; off <<= 1) sv += __shfl_xor(sv, off);
        if (l15 == 0) {
          int bi = bi2[rt][r];
          float rw = 2.f * slrs[bi] - sl[bi * 64 + bi];
          float lse = (__log2f(fmaxf(sv, 1e-37f)) + B[rt][r]) * LN2;
          tot += rw * lse;
        }
      }
    block_acc256(tot, scale, acc);
  }
}

// final FC (both sides) + loss finalize (block 0)
__global__ void fc2_k(const float* __restrict__ A1, const float* __restrict__ A2,
                      const float* __restrict__ wf, const float* __restrict__ bf,
                      float* __restrict__ lg1, float* __restrict__ lg2,
                      const double* __restrict__ acc, float* __restrict__ out_loss) {
  int n = blockIdx.x & 63;
  int side = blockIdx.x >> 6;
  const float* a = side ? A2 : A1;
  float* lg = side ? lg2 : lg1;
  float accv[5] = {0.f, 0.f, 0.f, 0.f, 0.f};
  for (int f = threadIdx.x; f < 16640; f += 1024) {
    float av = a[(size_t)n * 16640 + f];
    const float* wr = wf + (size_t)f * 5;
#pragma unroll
    for (int k = 0; k < 5; ++k) accv[k] = fmaf(av, wr[k], accv[k]);
  }
  __shared__ float red[16][5];
#pragma unroll
  for (int k = 0; k < 5; ++k) {
    float v = accv[k];
#pragma unroll
    for (int off = 32; off; off >>= 1) v += __shfl_down(v, off);
    if ((threadIdx.x & 63) == 0) red[threadIdx.x >> 6][k] = v;
  }
  __syncthreads();
  if (threadIdx.x == 0) {
#pragma unroll
    for (int k = 0; k < 5; ++k) {
      float s = bf[k];
#pragma unroll
      for (int i = 0; i < 16; ++i) s += red[i][k];
      lg[n * 5 + k] = s;
    }
    if (blockIdx.x == 0) *out_loss = (float)(*acc);
  }
}

extern "C" void kernel_launch(void* const* d_in, const int* in_sizes, int n_in,
                              void* d_out, int out_size, void* d_ws, size_t ws_size,
                              hipStream_t stream) {
  const float* aug1 = (const float*)d_in[0];
  const float* aug2 = (const float*)d_in[1];
  const float* sl = (const float*)d_in[2];
  const float* wconv[3] = {(const float*)d_in[3], (const float*)d_in[6], (const float*)d_in[9]};
  const float* gam[3]   = {(const float*)d_in[4], (const float*)d_in[7], (const float*)d_in[10]};
  const float* bet[3]   = {(const float*)d_in[5], (const float*)d_in[8], (const float*)d_in[11]};
  const float* wf = (const float*)d_in[12];
  const float* bf = (const float*)d_in[13];
  float* out = (float*)d_out;
  float* ws = (float*)d_ws;
  if (ws_size < (size_t)WS_TOTAL * sizeof(float)) return;

  double* acc = (double*)(ws + WS_ACC);
  float* bnA = ws + WS_BNA;
  float* bnB = ws + WS_BNB;
  float* ftab = ws + WS_FTAB;
  float* roww = ws + WS_ROWW;
  float* slrs = ws + WS_SLRS;
  short* wbf[3] = {(short*)(ws + WS_WBF1), (short*)(ws + WS_WBF2), (short*)(ws + WS_WBF3)};
  float* partS = ws + WS_PART1;
  float* partS2 = ws + WS_PART2;
  float* normsP = ws + WS_NORMS;
  float* bmaxP = ws + WS_BMAX;
  short* xpad = (short*)(ws + WS_XPAD);
  short* convb = (short*)(ws + WS_CONV);
  __hip_bfloat16* zb16 = (__hip_bfloat16*)(ws + WS_ZB16);
  short* zfragP = (short*)(ws + WS_ZFRAG);

  const int Lc[3]    = {1025, 514, 259};
  const int Lcp[3]   = {1028, 516, 260};
  const int Cout[3]  = {32, 64, 128};
  const int Tarr[3]  = {513, 258, 130};
  const float sig[3] = {2.f, 4.f, 8.f};

  float* A1 = out + O_A1;
  float* A2 = out + O_A2;

  prep_k<<<457, 256, 0, stream>>>(acc, sl, slrs, wconv[0], wconv[1], wconv[2],
                                  wbf[0], wbf[1], wbf[2], aug1, aug2, xpad);

  for (int d = 0; d < 3; ++d) {
    int T = Tarr[d];
    int T2 = 2 * T;
    int jt = (Lc[d] + 63) / 64;
    int NTt = (T2 + 15) >> 4;

    switch (d) {
      case 0: conv4_k<1, 8, 32, 1, 1032, 24><<<dim3(jt, 128, 1), 256, 0, stream>>>(xpad, wbf[0], convb, partS, partS2, Lc[d], Lcp[d]); break;
      case 1: conv4_k<32, 32, 64, 1, 528, 40><<<dim3(jt, 128, 1), 256, 0, stream>>>(xpad, wbf[1], convb, partS, partS2, Lc[d], Lcp[d]); break;
      default: conv4_k<64, 64, 128, 4, 272, 72><<<dim3(jt, 128, 4), 256, 0, stream>>>(xpad, wbf[2], convb, partS, partS2, Lc[d], Lcp[d]); break;
    }
    stats2_k<<<2 * Cout[d], 256, 0, stream>>>(partS, partS2, gam[d], bet[d], bnA, bnB, 64 * jt, BB * Lc[d], Cout[d]);
    {
      float* p1 = (d == 2) ? A1 : nullptr;
      float* p2 = (d == 2) ? A2 : nullptr;
      short* xn = (d == 2) ? nullptr : xpad;
      int TPn = (d == 0) ? 528 : (d == 1) ? 272 : 0;
      pool3_k<<<dim3((T + 31) / 32, Cout[d] / 32, 128), dim3(32, 8), 0, stream>>>(
          convb, bnA, bnB, p1, p2, zb16, zfragP, NTt, xn, TPn, Cout[d], Lc[d], Lcp[d], T);
    }

    double scale = 0.5 / (128.0 * (double)T);
    int tgx = (T2 + 63) / 64;
    int bgx = (T + 63) / 64;
    int nblk = tgx * BB + bgx * BB + T;
    switch (d) {
      case 0:
        norms_k<32><<<64, 1024, 0, stream>>>(zb16, normsP, bmaxP, zfragP, NTt, ftab, roww, T, sig[d]);
        loss_k<32><<<nblk, 256, 0, stream>>>(zfragP, zb16, ftab, roww, normsP, bmaxP, sl, slrs, T, NTt, tgx, bgx, scale, acc);
        break;
      case 1:
        norms_k<64><<<64, 1024, 0, stream>>>(zb16, normsP, bmaxP, zfragP, NTt, ftab, roww, T, sig[d]);
        loss_k<64><<<nblk, 256, 0, stream>>>(zfragP, zb16, ftab, roww, normsP, bmaxP, sl, slrs, T, NTt, tgx, bgx, scale, acc);
        break;
      default:
        norms_k<128><<<64, 1024, 0, stream>>>(zb16, normsP, bmaxP, zfragP, NTt, ftab, roww, T, sig[d]);
        loss_k<128><<<nblk, 256, 0, stream>>>(zfragP, zb16, ftab, roww, normsP, bmaxP, sl, slrs, T, NTt, tgx, bgx, scale, acc);
        break;
    }
  }
  fc2_k<<<128, 1024, 0, stream>>>(A1, A2, wf, bf, out + O_LG1, out + O_LG2, acc, out + O_LOSS);
}

// Round 22
// 202.909 us; speedup vs baseline: 1.0303x; 1.0145x over previous
//
#include <hip/hip_runtime.h>
#include <hip/hip_bf16.h>
#include <math.h>

#define BB 64
#define PB_STRIDE 1536      // >= 64 b * 17 jtiles
#define CONV_SIDE 2129920   // bf16 elems per side (64*128*260 max)

typedef __attribute__((ext_vector_type(8))) short short8;
typedef __attribute__((ext_vector_type(4))) short short4v;
typedef __attribute__((ext_vector_type(4))) float f32x4;

// workspace layout (floats)
#define WS_ACC    0
#define WS_BNA    8
#define WS_BNB    264
#define WS_FTAB   520
#define WS_ROWW   536
#define WS_SLRS   1064
#define WS_WBF1   1128     // 1024 shorts (32 o x 64 K)
#define WS_WBF2   2152     // 16384 shorts
#define WS_WBF3   10344    // 65536 shorts
#define WS_PART1  43112    // 393216
#define WS_PART2  436328   // 393216
#define WS_NORMS  829544   // 66560
#define WS_BMAX   896104   // 64
#define WS_XPAD   896168   // 2228224 floats padded bf16 conv inputs
#define WS_CONV   3124392  // 2129920 floats = 2 sides x CONV_SIDE bf16
#define WS_ZB16   5254312  // 1100000
#define WS_ZFRAG  6354312  // 1120000 floats (fragment-packed z)
#define WS_TOTAL  7474312

// d_out layout (floats)
#define O_LG1  0
#define O_LG2  320
#define O_A1   640
#define O_A2   (640 + 1064960)
#define O_LOSS (O_A2 + 1064960)

#define LOG2E 1.44269504f
#define LN2   0.69314718f

// hardware v_exp_f32: exact enough on our guaranteed arg range [-222, 110]
#define EXP2F(x) __builtin_amdgcn_exp2f(x)

__device__ __forceinline__ short f2bf(float f) {
  unsigned u = __float_as_uint(f);
  u += 0x7FFFu + ((u >> 16) & 1u);
  return (short)(u >> 16);
}
__device__ __forceinline__ float bfb2f(short s) {
  return __uint_as_float(((unsigned)(unsigned short)s) << 16);
}

// ---------- fused prep: init + all weight preps + aug pad (grid 457) ----------
__global__ void prep_k(double* acc, const float* __restrict__ sl, float* __restrict__ slrs,
                       const float* __restrict__ w1, const float* __restrict__ w2,
                       const float* __restrict__ w3, short* __restrict__ o1,
                       short* __restrict__ o2, short* __restrict__ o3,
                       const float* __restrict__ a1, const float* __restrict__ a2,
                       short* __restrict__ xp) {
  int bid = blockIdx.x;
  if (bid == 0) {
    if (threadIdx.x == 0) *acc = 0.0;
    if (threadIdx.x < 64) {
      int r = threadIdx.x;
      float s = 0.f;
      for (int c = 0; c < 64; ++c) s += sl[r * 64 + c];
      slrs[r] = s;
    }
    return;
  }
  if (bid <= 328) {
    int i = (bid - 1) * 256 + threadIdx.x;
    const float* w; short* ob; int CIN, CIPAD;
    if (i < 2048)        { w = w1; ob = o1; CIN = 1;  CIPAD = 8; }
    else if (i < 18432)  { i -= 2048;  w = w2; ob = o2; CIN = 32; CIPAD = 32; }
    else                 { i -= 18432; w = w3; ob = o3; CIN = 64; CIPAD = 64; }
    int KTOT = CIPAD * 8;
    int o = i / KTOT, q = i - o * KTOT;
    int k = q / CIPAD, ci = q - k * CIPAD;
    short v = 0;
    if (ci < CIN) v = f2bf(w[(o * CIN + ci) * 8 + k]);
    ob[i] = v;
    return;
  }
  int sb = bid - 329;
  int side = sb >> 6, b = sb & 63;
  const float* src = (side ? a2 : a1) + (size_t)b * 1024;
  short* dst = xp + (size_t)sb * 1032;
  for (int e = threadIdx.x; e < 1032; e += 256) {
    short v = 0;
    if (e >= 4 && e < 1028) v = f2bf(src[e - 4]);
    dst[e] = v;
  }
}

// ---------- K-permuted MFMA conv1d, weights staged to LDS (swizzled) ----------
template <int CIN, int CIPAD, int COUT, int OSPLIT, int XP, int LRS>
__launch_bounds__(256)
__global__ void conv4_k(const short* __restrict__ xbf, const short* __restrict__ wbf,
                        short* __restrict__ ybf, float* __restrict__ part_s,
                        float* __restrict__ part_s2, int Lc, int Lcp) {
  constexpr int KTOT = CIPAD * 8;
  constexpr int S = KTOT / 32;
  constexpr int COS = COUT / OSPLIT;
  constexpr int NT = COS / 16;
  constexpr int RSd = LRS / 2;
  constexpr int CP2 = CIPAD / 2;
  __shared__ __attribute__((aligned(16))) unsigned traw[72 * RSd];
  __shared__ __attribute__((aligned(16))) char wlds[COS * KTOT * 2];
  __shared__ float ps[4][COS], ps2[4][COS];
  const int tid = threadIdx.x;
  const int wave = tid >> 6, lane = tid & 63, l15 = lane & 15, l4 = lane >> 4;
  const int by = blockIdx.y;
  const int b = by & 63, side = by >> 6;
  const int o0 = blockIdx.z * COS;
  const int j0 = blockIdx.x * 64;
  const short* xb = xbf + (size_t)(side * 64 + b) * CIN * XP;
  short* yside = ybf + (size_t)side * CONV_SIDE;

  for (int idx = tid; idx < COS * (KTOT / 8); idx += 256) {
    int o = idx / (KTOT / 8);
    int q8 = idx - o * (KTOT / 8);
    short8 wv = *(const short8*)(wbf + (size_t)(o0 + o) * KTOT + q8 * 8);
    unsigned byte = (unsigned)((o * KTOT + q8 * 8) * 2) ^ (unsigned)((o & 7) << 4);
    *(short8*)(wlds + byte) = wv;
  }
  for (int idx = tid; idx < 9 * CP2; idx += 256) {
    int cp = idx & (CP2 - 1);
    int u = idx / CP2;
    int ci = cp * 2;
    short8 av = (short8){0, 0, 0, 0, 0, 0, 0, 0};
    short8 bv = (short8){0, 0, 0, 0, 0, 0, 0, 0};
    if (ci < CIN)     av = *(const short8*)(xb + (size_t)ci * XP + j0 + u * 8);
    if (ci + 1 < CIN) bv = *(const short8*)(xb + (size_t)(ci + 1) * XP + j0 + u * 8);
#pragma unroll
    for (int t = 0; t < 8; ++t)
      traw[(u * 8 + t) * RSd + cp] =
        ((unsigned)(unsigned short)av[t]) | (((unsigned)(unsigned short)bv[t]) << 16);
  }
  __syncthreads();

  f32x4 acc[NT];
#pragma unroll
  for (int nt = 0; nt < NT; ++nt) acc[nt] = (f32x4){0.f, 0.f, 0.f, 0.f};

  const int row = wave * 16 + l15;
  const unsigned wsw = (unsigned)((l15 & 7) << 4);
#pragma unroll
  for (int s = 0; s < S; ++s) {
    int k, cd;
    if (CIPAD == 8)       { k = s * 4 + l4; cd = 0; }
    else if (CIPAD == 32) { k = s;          cd = l4 * 4; }
    else                  { k = s >> 1;     cd = (s & 1) * 16 + l4 * 4; }
    short8 af = *(const short8*)(traw + (row + k) * RSd + cd);
#pragma unroll
    for (int nt = 0; nt < NT; ++nt) {
      unsigned wbyte = (unsigned)(((nt * 16 + l15) * KTOT + s * 32 + l4 * 8) * 2) ^ wsw;
      short8 wv = *(const short8*)(wlds + wbyte);
      acc[nt] = __builtin_amdgcn_mfma_f32_16x16x32_bf16(af, wv, acc[nt], 0, 0, 0);
    }
  }

  const int jbase = j0 + wave * 16 + l4 * 4;
#pragma unroll
  for (int nt = 0; nt < NT; ++nt) {
    int ol = nt * 16 + l15;
    size_t orow = ((size_t)b * COUT + (o0 + ol)) * Lcp;
    float s = 0.f, s2 = 0.f;
    if (jbase + 3 < Lc) {
      short4v sv = (short4v){f2bf(acc[nt][0]), f2bf(acc[nt][1]), f2bf(acc[nt][2]), f2bf(acc[nt][3])};
      *(short4v*)(yside + orow + jbase) = sv;
#pragma unroll
      for (int r = 0; r < 4; ++r) { float v = acc[nt][r]; s += v; s2 = fmaf(v, v, s2); }
    } else {
#pragma unroll
      for (int r = 0; r < 4; ++r) {
        if (jbase + r < Lc) {
          float v = acc[nt][r];
          yside[orow + jbase + r] = f2bf(v);
          s += v; s2 = fmaf(v, v, s2);
        }
      }
    }
    s  += __shfl_xor(s, 16);  s  += __shfl_xor(s, 32);
    s2 += __shfl_xor(s2, 16); s2 += __shfl_xor(s2, 32);
    if (lane < 16) { ps[wave][ol] = s; ps2[wave][ol] = s2; }
  }
  __syncthreads();
  int blk = b * gridDim.x + blockIdx.x;
  for (int o = tid; o < COS; o += 256) {
    size_t pi = (size_t)(side * COUT + o0 + o) * PB_STRIDE + blk;
    part_s [pi] = ps[0][o] + ps[1][o] + ps[2][o] + ps[3][o];
    part_s2[pi] = ps2[0][o] + ps2[1][o] + ps2[2][o] + ps2[3][o];
  }
}

// reduce conv partials -> bnA/bnB per (side, channel)
__global__ void stats2_k(const float* __restrict__ part_s, const float* __restrict__ part_s2,
                         const float* __restrict__ g, const float* __restrict__ beta,
                         float* __restrict__ bnA, float* __restrict__ bnB,
                         int nblk, int n, int COUT) {
  int bid = blockIdx.x;
  int c = bid % COUT;
  float s = 0.f, s2 = 0.f;
  for (int i = threadIdx.x; i < nblk; i += 256) {
    s += part_s[(size_t)bid * PB_STRIDE + i];
    s2 += part_s2[(size_t)bid * PB_STRIDE + i];
  }
#pragma unroll
  for (int off = 32; off; off >>= 1) { s += __shfl_down(s, off); s2 += __shfl_down(s2, off); }
  __shared__ float as[4], as2[4];
  if ((threadIdx.x & 63) == 0) { as[threadIdx.x >> 6] = s; as2[threadIdx.x >> 6] = s2; }
  __syncthreads();
  if (threadIdx.x == 0) {
    float S = as[0] + as[1] + as[2] + as[3];
    float S2 = as2[0] + as2[1] + as2[2] + as2[3];
    float fn = (float)n;
    float mu = S / fn;
    float var = S2 / fn - mu * mu;
    float A = g[c] * rsqrtf(var + 1e-5f);
    bnA[bid] = A;
    bnB[bid] = beta[c] - mu * A;
  }
}

// fused-sides BN-apply + ReLU + maxpool; writes zb, zfrag, optional pooled / next input
__global__ void pool3_k(const short* __restrict__ convb, const float* __restrict__ bnA,
                        const float* __restrict__ bnB, float* __restrict__ pd1,
                        float* __restrict__ pd2, __hip_bfloat16* __restrict__ zb,
                        short* __restrict__ zfrag, int NTt,
                        short* __restrict__ xnext, int TPn,
                        int C, int Lc, int Lcp, int Tout) {
  __shared__ float tile[32][33];
  int bz = blockIdx.z;
  int b = bz & 63, side = bz >> 6;
  const short* cs = convb + (size_t)side * CONV_SIDE;
  float* pooled = side ? pd2 : pd1;
  int zoff = side * Tout;
  int c0 = blockIdx.y * 32;
  int t0 = blockIdx.x * 32;
  int tx = threadIdx.x;
  int ty = threadIdx.y;
  int tid = ty * 32 + tx;
#pragma unroll
  for (int q = 0; q < 4; ++q) {
    int c = c0 + ty + q * 8;
    int t = t0 + tx;
    size_t xrow = xnext ? ((size_t)(side * 64 + b) * C + c) * TPn : 0;
    float v = 0.f;
    if (t < Tout) {
      const short* row = cs + ((size_t)b * C + c) * Lcp;
      float A = bnA[side * C + c], Bb = bnB[side * C + c];
      v = -3.0e38f;
      int p0 = 2 * t - 1;
      if (p0 >= 0) v = fmaxf(v, fmaxf(fmaf(A, bfb2f(row[p0]), Bb), 0.f));
      int p1 = 2 * t;
      if (p1 < Lc) v = fmaxf(v, fmaxf(fmaf(A, bfb2f(row[p1]), Bb), 0.f));
      if (pooled) pooled[((size_t)b * C + c) * Tout + t] = v;
      if (xnext) xnext[xrow + 4 + t] = f2bf(v);
    } else if (xnext && 4 + t < TPn) {
      xnext[xrow + 4 + t] = 0;
    }
    if (xnext && t0 == 0 && tx < 4) xnext[xrow + tx] = 0;
    tile[ty + q * 8][tx] = v;   // tile[c-off][t-off]
  }
  __syncthreads();
  int T2 = 2 * Tout;
#pragma unroll
  for (int q = 0; q < 4; ++q) {
    int t = t0 + ty + q * 8;
    int c = c0 + tx;
    if (t < Tout)
      zb[((size_t)b * T2 + zoff + t) * (size_t)C + c] = __float2bfloat16(tile[tx][ty + q * 8]);
  }
  if (tid < 128) {
    int t_off = tid & 31, cg = tid >> 5;
    if (t0 + t_off < Tout) {
      short8 v;
#pragma unroll
      for (int e = 0; e < 8; ++e) v[e] = f2bf(tile[cg * 8 + e][t_off]);
      int r = zoff + t0 + t_off;
      int ct = r >> 4, l15r = r & 15;
      int ch = c0 + cg * 8;
      int KST = C >> 5;
      int ks = ch >> 5, g4 = (ch >> 3) & 3;
      int lane2 = l15r + (g4 << 4);
      *(short8*)(zfrag + (((size_t)b * NTt + ct) * (size_t)KST + ks) * 512 + (size_t)lane2 * 8) = v;
    }
  }
}

// per-row norms + batch max; block 0 computes ftab/roww; each block zeroes zfrag pad
template <int C>
__global__ void norms_k(const __hip_bfloat16* __restrict__ zb, float* __restrict__ norms,
                        float* __restrict__ bmax, short* __restrict__ zfrag, int NTt,
                        float* __restrict__ ftab, float* __restrict__ roww,
                        int T, float sigma) {
  constexpr int KST = C / 32;
  int b = blockIdx.x;
  int T2 = 2 * T;
  __shared__ float fs[8];
  if (threadIdx.x < 8) {
    double mm = 2.0 / (1.0 + exp((double)threadIdx.x * (double)sigma));
    float f = (mm < 1e-6) ? 0.f : (float)mm;
    fs[threadIdx.x] = f;
    if (b == 0) ftab[threadIdx.x] = f;
  }
  __syncthreads();
  if (b == 0) {
    for (int i = threadIdx.x; i < T; i += 1024) {
      float s = fs[0];
#pragma unroll
      for (int d = 1; d < 8; ++d) s += fs[d] * ((i >= d ? 1.f : 0.f) + (i + d < T ? 1.f : 0.f));
      roww[i] = 2.f * s - fs[0];
    }
  }
  int rem = T2 & 15;
  if (rem) {
    for (int u = threadIdx.x; u < KST * 64; u += 1024) {
      int ks = u >> 6, l = u & 63;
      if ((l & 15) >= rem)
        *(short8*)(zfrag + (((size_t)b * NTt + (NTt - 1)) * (size_t)KST + ks) * 512 + (size_t)l * 8) =
            (short8){0, 0, 0, 0, 0, 0, 0, 0};
    }
  }
  const __hip_bfloat16* zbb = zb + (size_t)b * T2 * C;
  int q = threadIdx.x & 3, r0 = threadIdx.x >> 2;
  float nm = 0.f;
  for (int r = r0; r < T2; r += 256) {
    float s = 0.f;
    const __hip_bfloat16* p = zbb + (size_t)r * C + q * (C / 4);
#pragma unroll
    for (int v = 0; v < C / 32; ++v) {
      short8 sv = *(const short8*)(p + v * 8);
#pragma unroll
      for (int e = 0; e < 8; ++e) { float f = bfb2f(sv[e]); s = fmaf(f, f, s); }
    }
    s += __shfl_xor(s, 1); s += __shfl_xor(s, 2);
    float nr = sqrtf(s);
    if (q == 0) norms[(size_t)b * T2 + r] = nr;
    nm = fmaxf(nm, nr);
  }
#pragma unroll
  for (int off = 32; off; off >>= 1) nm = fmaxf(nm, __shfl_xor(nm, off));
  __shared__ float pm[16];
  if ((threadIdx.x & 63) == 0) pm[threadIdx.x >> 6] = nm;
  __syncthreads();
  if (threadIdx.x == 0) {
    float m = 0.f;
#pragma unroll
    for (int i = 0; i < 16; ++i) m = fmaxf(m, pm[i]);
    bmax[b] = m;
  }
}

__device__ __forceinline__ void block_acc256(float v, double scale, double* acc) {
#pragma unroll
  for (int off = 32; off; off >>= 1) v += __shfl_down(v, off);
  __shared__ float part[4];
  if ((threadIdx.x & 63) == 0) part[threadIdx.x >> 6] = v;
  __syncthreads();
  if (threadIdx.x == 0)
    atomicAdd(acc, (double)(part[0] + part[1] + part[2] + part[3]) * scale);
}

// ---------- FUSED loss kernel: temporal (zfrag MFMA) | band | instance ----------
// XCD-aware swizzle within temporal/band ranges; temporal loop = R19-proven 4-deep.
template <int C>
__launch_bounds__(256)
__global__ void loss_k(const short* __restrict__ zfrag, const __hip_bfloat16* __restrict__ zb,
                       const float* __restrict__ ftab, const float* __restrict__ roww,
                       const float* __restrict__ norms, const float* __restrict__ bmax,
                       const float* __restrict__ sl, const float* __restrict__ slrs,
                       int T, int NTt, int tgx, int bgx,
                       double scale, double* __restrict__ acc) {
  constexpr int KST = C / 32;
  constexpr int LOGK = (KST == 1) ? 0 : (KST == 2) ? 1 : 2;
  constexpr int SB_BAND = (78 * (C + 1) + 8) * 4;
  constexpr int SB_INST = 256 * C + 128 * 4 + 16 + 16;
  constexpr int SMEM = SB_BAND > SB_INST ? SB_BAND : SB_INST;
  __shared__ __attribute__((aligned(16))) char smem[SMEM];
  const int tid = threadIdx.x;
  const int wave = tid >> 6, lane = tid & 63, l15 = lane & 15, l4 = lane >> 4;
  const int T2 = 2 * T;
  const int nbt = tgx * BB;
  const int nbb = bgx * BB;
  const int bid = blockIdx.x;

  if (bid < nbt) {
    // ================= temporal part =================
    const int wg = (bid & 7) * (nbt >> 3) + (bid >> 3);  // XCD chunking
    const int bx = wg % tgx, b = wg / tgx;
    const int i0 = bx * 64 + wave * 16;
    const int myti = i0 >> 4;
    const bool alive = myti < NTt;
    const short* zf = zfrag + (size_t)b * NTt * KST * 512;

    short8 af[KST];
#pragma unroll
    for (int ks = 0; ks < KST; ++ks) {
      af[ks] = (short8){0, 0, 0, 0, 0, 0, 0, 0};
      if (alive) af[ks] = *(const short8*)(zf + ((size_t)myti * KST + ks) * 512 + lane * 8);
    }
    const float Nb = bmax[b];
    float B[4], se[4];
    int ig[4]; bool dlane[4];
#pragma unroll
    for (int r = 0; r < 4; ++r) {
      ig[r] = i0 + l4 * 4 + r;
      int ix = ig[r] < T2 ? ig[r] : T2 - 1;
      B[r] = fmaxf(norms[(size_t)b * T2 + ix] * Nb * LOG2E - 110.f, 0.f);
      se[r] = 0.f;
      dlane[r] = (l15 == l4 * 4 + r);
    }

    auto proc = [&](int ct, f32x4 d) {
      if (alive && ct == myti) {
#pragma unroll
        for (int r = 0; r < 4; ++r)
          se[r] += dlane[r] ? 0.f : EXP2F(fmaf(d[r], LOG2E, -B[r]));
      } else {
#pragma unroll
        for (int r = 0; r < 4; ++r)
          se[r] += EXP2F(fmaf(d[r], LOG2E, -B[r]));
      }
    };

    int ct = 0;
    for (; ct + 3 < NTt; ct += 4) {
      short8 bb[4][KST];
#pragma unroll
      for (int u = 0; u < 4; ++u)
#pragma unroll
        for (int ks = 0; ks < KST; ++ks)
          bb[u][ks] = *(const short8*)(zf + ((size_t)(ct + u) * KST + ks) * 512 + lane * 8);
      f32x4 dd[4];
#pragma unroll
      for (int u = 0; u < 4; ++u) {
        dd[u] = (f32x4){0.f, 0.f, 0.f, 0.f};
#pragma unroll
        for (int ks = 0; ks < KST; ++ks)
          dd[u] = __builtin_amdgcn_mfma_f32_16x16x32_bf16(af[ks], bb[u][ks], dd[u], 0, 0, 0);
      }
#pragma unroll
      for (int u = 0; u < 4; ++u) proc(ct + u, dd[u]);
    }
    for (; ct < NTt; ++ct) {
      short8 b0[KST];
#pragma unroll
      for (int ks = 0; ks < KST; ++ks)
        b0[ks] = *(const short8*)(zf + ((size_t)ct * KST + ks) * 512 + lane * 8);
      f32x4 d0 = {0.f, 0.f, 0.f, 0.f};
#pragma unroll
      for (int ks = 0; ks < KST; ++ks)
        d0 = __builtin_amdgcn_mfma_f32_16x16x32_bf16(af[ks], b0[ks], d0, 0, 0, 0);
      proc(ct, d0);
    }

    const float npad = (float)(NTt * 16 - T2);
    float tot = 0.f;
#pragma unroll
    for (int r = 0; r < 4; ++r) {
      float sv = se[r];
#pragma unroll
      for (int off = 1; off < 16; off <<= 1) sv += __shfl_xor(sv, off);
      sv -= npad * EXP2F(-B[r]);
      if (l15 == 0 && ig[r] < T2) {
        int ii = ig[r] < T ? ig[r] : ig[r] - T;
        float lse = (__log2f(fmaxf(sv, 1e-37f)) + B[r]) * LN2;
        tot += roww[ii] * lse;
      }
    }
    block_acc256(tot, scale, acc);

  } else if (bid < nbt + nbb) {
    // ================= band part =================
    const int r2 = bid - nbt;
    const int wg = (r2 & 7) * (nbb >> 3) + (r2 >> 3);    // XCD chunking
    const int bx = wg % bgx, b = wg / bgx;
    const int ii0 = bx * 64;
    float* Y = (float*)smem;                              // [78][C+1]
    float* f = (float*)(smem + 78 * (C + 1) * 4);         // [8]
    if (tid < 8) f[tid] = ftab[tid];
    const __hip_bfloat16* zbb = zb + (size_t)b * T2 * C;
    for (int idx = tid; idx < 78 * (C / 8); idx += 256) {
      int rr = idx / (C / 8), k = (idx % (C / 8)) * 8;
      int ii = ii0 - 7 + rr;
      if (ii >= 0 && ii < T) {
        short8 v1 = *(const short8*)(zbb + (size_t)ii * C + k);
        short8 v2 = *(const short8*)(zbb + (size_t)(T + ii) * C + k);
#pragma unroll
        for (int e = 0; e < 8; ++e) Y[rr * (C + 1) + k + e] = bfb2f(v1[e]) + bfb2f(v2[e]);
      } else {
#pragma unroll
        for (int e = 0; e < 8; ++e) Y[rr * (C + 1) + k + e] = 0.f;
      }
    }
    float p2 = 0.f;
    for (int idx = tid; idx < 64 * (C / 8); idx += 256) {
      int rr = idx / (C / 8), k = (idx % (C / 8)) * 8;
      int ii = ii0 + rr;
      if (ii < T) {
        short8 v1 = *(const short8*)(zbb + (size_t)ii * C + k);
        short8 v2 = *(const short8*)(zbb + (size_t)(T + ii) * C + k);
#pragma unroll
        for (int e = 0; e < 8; ++e) {
          float f1 = bfb2f(v1[e]), f2 = bfb2f(v2[e]);
          p2 = fmaf(f1, f1, p2); p2 = fmaf(f2, f2, p2);
        }
      }
    }
    __syncthreads();
    const int m = tid & 63, q = tid >> 6;
    float p = 0.f;
    if (ii0 + m < T) {
      int rr = m + 7;
      constexpr int SL = C / 4;
      for (int k = q * SL; k < (q + 1) * SL; ++k) {
        float g = f[0] * Y[rr * (C + 1) + k];
#pragma unroll
        for (int dd = 1; dd < 8; ++dd)
          g = fmaf(f[dd], Y[(rr - dd) * (C + 1) + k] + Y[(rr + dd) * (C + 1) + k], g);
        p = fmaf(Y[rr * (C + 1) + k], g, p);
      }
    }
    block_acc256(f[0] * p2 - p, scale, acc);

  } else {
    // ================= instance part (sl from global) =================
    const int t = bid - nbt - nbb;
    char* rz = smem;                                        // 256*C bytes
    float* normsh = (float*)(smem + 256 * C);               // [128]
    float* pmx = (float*)(smem + 256 * C + 512);            // [4]
    for (int idx = tid; idx < 128 * (C / 8); idx += 256) {
      int ln = idx & 63;
      int ks = (idx >> 6) & (KST - 1);
      int t16 = idx >> (6 + LOGK);
      int r = t16 * 16 + (ln & 15);
      size_t grow = (size_t)(r & 63) * T2 + ((r < 64) ? t : T + t);
      *(short8*)(rz + (size_t)idx * 16) = *(const short8*)(zb + grow * C + ks * 32 + (ln >> 4) * 8);
    }
    if (tid < 128) normsh[tid] = norms[(size_t)(tid & 63) * T2 + ((tid < 64) ? t : T + t)];
    __syncthreads();
    float nv = (tid < 128) ? normsh[tid] : 0.f;
#pragma unroll
    for (int off = 32; off; off >>= 1) nv = fmaxf(nv, __shfl_xor(nv, off));
    if (lane == 0) pmx[wave] = nv;
    __syncthreads();
    const float Nt = fmaxf(fmaxf(pmx[0], pmx[1]), fmaxf(pmx[2], pmx[3]));

    short8 af[2][KST];
#pragma unroll
    for (int rt = 0; rt < 2; ++rt)
#pragma unroll
      for (int ks = 0; ks < KST; ++ks)
        af[rt][ks] = *(const short8*)(rz + ((((wave * 2 + rt) * KST + ks) << 10) | (lane << 4)));
    float B[2][4], se[2][4], w4[2][4][4];
    int bi2[2][4]; bool dlane[4];
#pragma unroll
    for (int r = 0; r < 4; ++r) dlane[r] = (l15 == l4 * 4 + r);
#pragma unroll
    for (int rt = 0; rt < 2; ++rt)
#pragma unroll
      for (int r = 0; r < 4; ++r) {
        int igv = wave * 32 + rt * 16 + l4 * 4 + r;
        int bi = igv & 63;
        B[rt][r] = fmaxf(normsh[igv] * Nt * LOG2E - 110.f, 0.f);
        se[rt][r] = 0.f;
        bi2[rt][r] = bi;
#pragma unroll
        for (int c4 = 0; c4 < 4; ++c4) w4[rt][r][c4] = sl[bi * 64 + ((l15 + 16 * c4) & 63)];
      }
    float wdot = 0.f;

#pragma unroll
    for (int rt = 0; rt < 2; ++rt) {
      int ri0 = wave * 32 + rt * 16;
#pragma unroll
      for (int ct = 0; ct < 8; ++ct) {
        f32x4 d = {0.f, 0.f, 0.f, 0.f};
#pragma unroll
        for (int ks = 0; ks < KST; ++ks) {
          short8 bv = *(const short8*)(rz + (((ct * KST + ks) << 10) | (lane << 4)));
          d = __builtin_amdgcn_mfma_f32_16x16x32_bf16(af[rt][ks], bv, d, 0, 0, 0);
        }
        if (ri0 == ct * 16) {
#pragma unroll
          for (int r = 0; r < 4; ++r) {
            float dv = d[r];
            se[rt][r] += dlane[r] ? 0.f : EXP2F(fmaf(dv, LOG2E, -B[rt][r]));
            wdot = fmaf(dlane[r] ? 0.f : w4[rt][r][ct & 3], dv, wdot);
          }
        } else {
#pragma unroll
          for (int r = 0; r < 4; ++r) {
            float dv = d[r];
            se[rt][r] += EXP2F(fmaf(dv, LOG2E, -B[rt][r]));
            wdot = fmaf(w4[rt][r][ct & 3], dv, wdot);
          }
        }
      }
    }
    float tot = -wdot;
#pragma unroll
    for (int rt = 0; rt < 2; ++rt)
#pragma unroll
      for (int r = 0; r < 4; ++r) {
        float sv = se[rt][r];
#pragma unroll
        for (int off = 1; off < 16; off <<= 1) sv += __shfl_xor(sv, off);
        if (l15 == 0) {
          int bi = bi2[rt][r];
          float rw = 2.f * slrs[bi] - sl[bi * 64 + bi];
          float lse = (__log2f(fmaxf(sv, 1e-37f)) + B[rt][r]) * LN2;
          tot += rw * lse;
        }
      }
    block_acc256(tot, scale, acc);
  }
}

// final FC (both sides) + loss finalize (block 0)
__global__ void fc2_k(const float* __restrict__ A1, const float* __restrict__ A2,
                      const float* __restrict__ wf, const float* __restrict__ bf,
                      float* __restrict__ lg1, float* __restrict__ lg2,
                      const double* __restrict__ acc, float* __restrict__ out_loss) {
  int n = blockIdx.x & 63;
  int side = blockIdx.x >> 6;
  const float* a = side ? A2 : A1;
  float* lg = side ? lg2 : lg1;
  float accv[5] = {0.f, 0.f, 0.f, 0.f, 0.f};
  for (int f = threadIdx.x; f < 16640; f += 1024) {
    float av = a[(size_t)n * 16640 + f];
    const float* wr = wf + (size_t)f * 5;
#pragma unroll
    for (int k = 0; k < 5; ++k) accv[k] = fmaf(av, wr[k], accv[k]);
  }
  __shared__ float red[16][5];
#pragma unroll
  for (int k = 0; k < 5; ++k) {
    float v = accv[k];
#pragma unroll
    for (int off = 32; off; off >>= 1) v += __shfl_down(v, off);
    if ((threadIdx.x & 63) == 0) red[threadIdx.x >> 6][k] = v;
  }
  __syncthreads();
  if (threadIdx.x == 0) {
#pragma unroll
    for (int k = 0; k < 5; ++k) {
      float s = bf[k];
#pragma unroll
      for (int i = 0; i < 16; ++i) s += red[i][k];
      lg[n * 5 + k] = s;
    }
    if (blockIdx.x == 0) *out_loss = (float)(*acc);
  }
}

extern "C" void kernel_launch(void* const* d_in, const int* in_sizes, int n_in,
                              void* d_out, int out_size, void* d_ws, size_t ws_size,
                              hipStream_t stream) {
  const float* aug1 = (const float*)d_in[0];
  const float* aug2 = (const float*)d_in[1];
  const float* sl = (const float*)d_in[2];
  const float* wconv[3] = {(const float*)d_in[3], (const float*)d_in[6], (const float*)d_in[9]};
  const float* gam[3]   = {(const float*)d_in[4], (const float*)d_in[7], (const float*)d_in[10]};
  const float* bet[3]   = {(const float*)d_in[5], (const float*)d_in[8], (const float*)d_in[11]};
  const float* wf = (const float*)d_in[12];
  const float* bf = (const float*)d_in[13];
  float* out = (float*)d_out;
  float* ws = (float*)d_ws;
  if (ws_size < (size_t)WS_TOTAL * sizeof(float)) return;

  double* acc = (double*)(ws + WS_ACC);
  float* bnA = ws + WS_BNA;
  float* bnB = ws + WS_BNB;
  float* ftab = ws + WS_FTAB;
  float* roww = ws + WS_ROWW;
  float* slrs = ws + WS_SLRS;
  short* wbf[3] = {(short*)(ws + WS_WBF1), (short*)(ws + WS_WBF2), (short*)(ws + WS_WBF3)};
  float* partS = ws + WS_PART1;
  float* partS2 = ws + WS_PART2;
  float* normsP = ws + WS_NORMS;
  float* bmaxP = ws + WS_BMAX;
  short* xpad = (short*)(ws + WS_XPAD);
  short* convb = (short*)(ws + WS_CONV);
  __hip_bfloat16* zb16 = (__hip_bfloat16*)(ws + WS_ZB16);
  short* zfragP = (short*)(ws + WS_ZFRAG);

  const int Lc[3]    = {1025, 514, 259};
  const int Lcp[3]   = {1028, 516, 260};
  const int Cout[3]  = {32, 64, 128};
  const int Tarr[3]  = {513, 258, 130};
  const float sig[3] = {2.f, 4.f, 8.f};

  float* A1 = out + O_A1;
  float* A2 = out + O_A2;

  prep_k<<<457, 256, 0, stream>>>(acc, sl, slrs, wconv[0], wconv[1], wconv[2],
                                  wbf[0], wbf[1], wbf[2], aug1, aug2, xpad);

  for (int d = 0; d < 3; ++d) {
    int T = Tarr[d];
    int T2 = 2 * T;
    int jt = (Lc[d] + 63) / 64;
    int NTt = (T2 + 15) >> 4;

    switch (d) {
      case 0: conv4_k<1, 8, 32, 1, 1032, 24><<<dim3(jt, 128, 1), 256, 0, stream>>>(xpad, wbf[0], convb, partS, partS2, Lc[d], Lcp[d]); break;
      case 1: conv4_k<32, 32, 64, 1, 528, 40><<<dim3(jt, 128, 1), 256, 0, stream>>>(xpad, wbf[1], convb, partS, partS2, Lc[d], Lcp[d]); break;
      default: conv4_k<64, 64, 128, 4, 272, 72><<<dim3(jt, 128, 4), 256, 0, stream>>>(xpad, wbf[2], convb, partS, partS2, Lc[d], Lcp[d]); break;
    }
    stats2_k<<<2 * Cout[d], 256, 0, stream>>>(partS, partS2, gam[d], bet[d], bnA, bnB, 64 * jt, BB * Lc[d], Cout[d]);
    {
      float* p1 = (d == 2) ? A1 : nullptr;
      float* p2 = (d == 2) ? A2 : nullptr;
      short* xn = (d == 2) ? nullptr : xpad;
      int TPn = (d == 0) ? 528 : (d == 1) ? 272 : 0;
      pool3_k<<<dim3((T + 31) / 32, Cout[d] / 32, 128), dim3(32, 8), 0, stream>>>(
          convb, bnA, bnB, p1, p2, zb16, zfragP, NTt, xn, TPn, Cout[d], Lc[d], Lcp[d], T);
    }

    double scale = 0.5 / (128.0 * (double)T);
    int tgx = (T2 + 63) / 64;
    int bgx = (T + 63) / 64;
    int nblk = tgx * BB + bgx * BB + T;
    switch (d) {
      case 0:
        norms_k<32><<<64, 1024, 0, stream>>>(zb16, normsP, bmaxP, zfragP, NTt, ftab, roww, T, sig[d]);
        loss_k<32><<<nblk, 256, 0, stream>>>(zfragP, zb16, ftab, roww, normsP, bmaxP, sl, slrs, T, NTt, tgx, bgx, scale, acc);
        break;
      case 1:
        norms_k<64><<<64, 1024, 0, stream>>>(zb16, normsP, bmaxP, zfragP, NTt, ftab, roww, T, sig[d]);
        loss_k<64><<<nblk, 256, 0, stream>>>(zfragP, zb16, ftab, roww, normsP, bmaxP, sl, slrs, T, NTt, tgx, bgx, scale, acc);
        break;
      default:
        norms_k<128><<<64, 1024, 0, stream>>>(zb16, normsP, bmaxP, zfragP, NTt, ftab, roww, T, sig[d]);
        loss_k<128><<<nblk, 256, 0, stream>>>(zfragP, zb16, ftab, roww, normsP, bmaxP, sl, slrs, T, NTt, tgx, bgx, scale, acc);
        break;
    }
  }
  fc2_k<<<128, 1024, 0, stream>>>(A1, A2, wf, bf, out + O_LG1, out + O_LG2, acc, out + O_LOSS);
}